// Round 2
// baseline (831.747 us; speedup 1.0000x reference)
//
#include <hip/hip_runtime.h>
#include <cstdint>
#include <cmath>

// ---------------------------------------------------------------------------
// Mamba3 block forward, MI355X (gfx950).
// B=2, S=4096 (8192 tokens), D_MODEL=1024, D_INNER=2048, NHEADS=32, HD=64,
// D_STATE=64, CHUNK=64, D_MLP=2560, PROJ=9248.
// Workspace budget: ~251.5 MiB. x2 lives in d_out.
//
// R1: gemm_proj -> 256^2 8-phase counted-vmcnt schedule: 207 -> 162 us
//     (= 848 TF, matching the m248 K=1024 reference for this structure).
// R2: MLP gu GEMM (M=8192,N=5120,K=1024) ported to the same verified
//     structure via generic gemm256<MODE> (runtime NT/lda/ldc/nbx).
//     out/down GEMMs stay on gemm_bt: N=1024 -> only 128 blocks at 256^2
//     tiles = half the CUs idle (computed regression, ~72 vs 52 us).
// ---------------------------------------------------------------------------

typedef __bf16 bf16;
typedef __bf16 bf16x2 __attribute__((ext_vector_type(2)));
typedef __bf16 bf16x4 __attribute__((ext_vector_type(4)));
typedef __bf16 bf16x8 __attribute__((ext_vector_type(8)));
typedef float fx4 __attribute__((ext_vector_type(4)));

#define DEV __device__ __forceinline__

// ---- workspace layout (bytes) ---------------------------------------------
#define OFF_PROJ    0ull
#define OFF_HHI     134217728ull   // 8192x1024 bf16 (h hi) ; later h2_bf
#define OFF_HLO     150994944ull   // 8192x1024 bf16 (h lo) ; later S (chunk sums, 512KB)
#define OFF_WTIN    167772160ull   // 8192x1024 bf16
#define OFF_WTHI    184549376ull   // 1152x1024 bf16
#define OFF_WTLO    186908672ull   // 1152x1024 bf16
#define OFF_PROJT   189267968ull   // 8192x1152 f32 (dt,theta) -- dead after rope
#define OFF_BX      189267968ull   // 4096x4096 bf16 (written at ssd1, overlays projT)
#define OFF_STATES  222822400ull   // 4096x4096 bf16 -> FS in place; dead after ssd3
#define OFF_WTOUT   222822400ull   // 1024x2048 bf16 (after ssd3, overlays states)
#define OFF_WTGU    227016704ull   // 5120x1024 bf16 (after ssd3)
#define OFF_WTD     237502464ull   // 1024x2560 bf16 (after ssd3)
#define OFF_ABUF    256376832ull   // 8192x32 f32 (per-token A)
#define OFF_XSUM    257425408ull   // 8192x32 f32
#define OFF_ROWSUM  258473984ull   // (2,64,32,64) f32
#define OFF_EXPA    260571136ull   // (2,64,32,64) f32
#define OFF_DCHUNK  262668288ull   // (2,64,32) f32
#define OFF_GAMMA   262684672ull   // 8192x32 f32
#define WS_NEEDED   263733248ull

#define OFF_GU      0ull
#define OFF_MBF     83886080ull

// ---------------------------------------------------------------------------
DEV void async_copy16(void* lds, const void* gptr) {
  __builtin_amdgcn_global_load_lds(
      (const __attribute__((address_space(1))) unsigned int*)(gptr),
      (__attribute__((address_space(3))) unsigned int*)(lds),
      16, 0, 0);
}

DEV float warp_sum64(float v) {
  #pragma unroll
  for (int o = 32; o; o >>= 1) v += __shfl_xor(v, o);
  return v;
}

DEV float red16(float v) {   // reduce across 16-lane groups (cc dimension)
  v += __shfl_xor(v, 1); v += __shfl_xor(v, 2);
  v += __shfl_xor(v, 4); v += __shfl_xor(v, 8);
  return v;
}

DEV float softplus_f(float x) { return x > 20.f ? x : log1pf(expf(x)); }
DEV float sigmoid_f(float x) { return 1.f / (1.f + expf(-x)); }

// ---------------------------------------------------------------------------
__global__ __launch_bounds__(256) void transpose_cast(
    const float* __restrict__ src, int ld, int col0,
    bf16* __restrict__ dst, int R, int C)
{
  __shared__ float tile[32][33];
  const int c0 = blockIdx.x * 32, r0 = blockIdx.y * 32;
  const int tx = threadIdx.x & 31, ty = threadIdx.x >> 5;
  #pragma unroll
  for (int ii = 0; ii < 4; ++ii) {
    int i = ty + ii * 8;
    int c = c0 + tx;
    tile[i][tx] = (c < C) ? src[(size_t)(r0 + i) * ld + col0 + c] : 0.f;
  }
  __syncthreads();
  #pragma unroll
  for (int ii = 0; ii < 4; ++ii) {
    int i = ty + ii * 8;
    dst[(size_t)(c0 + i) * R + r0 + tx] = (bf16)tile[tx][i];
  }
}

__global__ __launch_bounds__(256) void transpose_cast_hilo(
    const float* __restrict__ src, int ld, int col0,
    bf16* __restrict__ dhi, bf16* __restrict__ dlo, int R, int C)
{
  __shared__ float tile[32][33];
  const int c0 = blockIdx.x * 32, r0 = blockIdx.y * 32;
  const int tx = threadIdx.x & 31, ty = threadIdx.x >> 5;
  #pragma unroll
  for (int ii = 0; ii < 4; ++ii) {
    int i = ty + ii * 8;
    int c = c0 + tx;
    tile[i][tx] = (c < C) ? src[(size_t)(r0 + i) * ld + col0 + c] : 0.f;
  }
  __syncthreads();
  #pragma unroll
  for (int ii = 0; ii < 4; ++ii) {
    int i = ty + ii * 8;
    float v = tile[tx][i];
    bf16 hi = (bf16)v;
    size_t o = (size_t)(c0 + i) * R + r0 + tx;
    dhi[o] = hi;
    dlo[o] = (bf16)(v - (float)hi);
  }
}

// ---------------------------------------------------------------------------
__global__ __launch_bounds__(256) void rmsnorm_kernel(
    const float* __restrict__ x, const float* __restrict__ w,
    bf16* __restrict__ hi, bf16* __restrict__ lo)
{
  __shared__ float red[4];
  const size_t row = blockIdx.x;
  const int tid = threadIdx.x;
  float4 v = ((const float4*)(x + row * 1024))[tid];
  float ss = v.x * v.x + v.y * v.y + v.z * v.z + v.w * v.w;
  ss = warp_sum64(ss);
  if ((tid & 63) == 0) red[tid >> 6] = ss;
  __syncthreads();
  float tot = red[0] + red[1] + red[2] + red[3];
  float s = rsqrtf(tot * (1.f / 1024.f) + 1e-5f);
  float4 wv = ((const float4*)w)[tid];
  float h0 = v.x * s * wv.x, h1 = v.y * s * wv.y, h2 = v.z * s * wv.z, h3 = v.w * s * wv.w;
  bf16x4 hv = { (bf16)h0, (bf16)h1, (bf16)h2, (bf16)h3 };
  *(bf16x4*)(hi + row * 1024 + tid * 4) = hv;
  if (lo) {
    bf16x4 lv = { (bf16)(h0 - (float)hv[0]), (bf16)(h1 - (float)hv[1]),
                  (bf16)(h2 - (float)hv[2]), (bf16)(h3 - (float)hv[3]) };
    *(bf16x4*)(lo + row * 1024 + tid * 4) = lv;
  }
}

// ---------------------------------------------------------------------------
// Generic bf16 GEMM (m97 structure). MODE: 1=bf16 store, 2=f32 v+resid
// Kept for N=1024 GEMMs (out/down) where 256^2 tiles under-fill the grid.
template <int MODE>
__global__ __launch_bounds__(256) void gemm_bt(
    const bf16* A, const bf16* B, void* Cout, const float* resid,
    int K, int lda, int ldc)
{
  __shared__ bf16 As[128 * 64];
  __shared__ bf16 Bs[128 * 64];
  const int tid = threadIdx.x, wid = tid >> 6, lane = tid & 63;
  const int m0 = blockIdx.y * 128, n0 = blockIdx.x * 128;
  const int wm = (wid & 1) * 64, wn = (wid >> 1) * 64;
  fx4 acc[4][4];
  #pragma unroll
  for (int i = 0; i < 4; ++i)
    #pragma unroll
    for (int j = 0; j < 4; ++j) { fx4 z = {0.f, 0.f, 0.f, 0.f}; acc[i][j] = z; }

  const int srow = wid * 32 + (lane >> 3);
  const int slot = lane & 7;

  for (int k0 = 0; k0 < K; k0 += 64) {
    __syncthreads();
    #pragma unroll
    for (int i = 0; i < 4; ++i) {
      int m = srow + i * 8;
      int cA = ((slot ^ (m & 7)) * 8);
      async_copy16(&As[wid * 2048 + i * 512], A + (size_t)(m0 + m) * lda + k0 + cA);
    }
    #pragma unroll
    for (int i = 0; i < 4; ++i) {
      int n = srow + i * 8;
      int cB = ((slot ^ (n & 7)) * 8);
      async_copy16(&Bs[wid * 2048 + i * 512], B + (size_t)(n0 + n) * K + k0 + cB);
    }
    __syncthreads();
    #pragma unroll
    for (int kk = 0; kk < 2; ++kk) {
      bf16x8 af[4], bfr[4];
      #pragma unroll
      for (int i = 0; i < 4; ++i) {
        int mm = wm + i * 16 + (lane & 15);
        int sA = (kk * 4 + (lane >> 4)) ^ (mm & 7);
        af[i] = *(const bf16x8*)&As[mm * 64 + sA * 8];
        int nn = wn + i * 16 + (lane & 15);
        int sB = (kk * 4 + (lane >> 4)) ^ (nn & 7);
        bfr[i] = *(const bf16x8*)&Bs[nn * 64 + sB * 8];
      }
      #pragma unroll
      for (int i = 0; i < 4; ++i)
        #pragma unroll
        for (int j = 0; j < 4; ++j)
          acc[i][j] = __builtin_amdgcn_mfma_f32_16x16x32_bf16(af[i], bfr[j], acc[i][j], 0, 0, 0);
    }
  }
  const int r0 = (lane >> 4) * 4, cc = lane & 15;
  #pragma unroll
  for (int i = 0; i < 4; ++i) {
    #pragma unroll
    for (int j = 0; j < 4; ++j) {
      #pragma unroll
      for (int r = 0; r < 4; ++r) {
        int m = m0 + wm + i * 16 + r0 + r;
        int n = n0 + wn + j * 16 + cc;
        size_t off = (size_t)m * ldc + n;
        float v = acc[i][j][r];
        if (MODE == 1) ((bf16*)Cout)[off] = (bf16)v;
        else ((float*)Cout)[off] = v + resid[off];
      }
    }
  }
}

// ---------------------------------------------------------------------------
// Fused hi/lo tail GEMM: out = Ahi*Whi^T + Ahi*Wlo^T + Alo*Whi^T (f32 out).
// M=8192, N=1152, K=1024, ldc=1152. 64KB LDS (4 tiles).
__global__ __launch_bounds__(256) void gemm_tail(
    const bf16* Ahi, const bf16* Alo, const bf16* Whi, const bf16* Wlo,
    float* Cout)
{
  __shared__ bf16 Ah[128 * 64], Al[128 * 64], Bh[128 * 64], Bl[128 * 64];
  const int tid = threadIdx.x, wid = tid >> 6, lane = tid & 63;
  const int m0 = blockIdx.y * 128, n0 = blockIdx.x * 128;
  const int wm = (wid & 1) * 64, wn = (wid >> 1) * 64;
  fx4 acc[4][4];
  #pragma unroll
  for (int i = 0; i < 4; ++i)
    #pragma unroll
    for (int j = 0; j < 4; ++j) { fx4 z = {0.f, 0.f, 0.f, 0.f}; acc[i][j] = z; }

  const int srow = wid * 32 + (lane >> 3);
  const int slot = lane & 7;

  for (int k0 = 0; k0 < 1024; k0 += 64) {
    __syncthreads();
    #pragma unroll
    for (int i = 0; i < 4; ++i) {
      int m = srow + i * 8;
      int cA = ((slot ^ (m & 7)) * 8);
      size_t ao = (size_t)(m0 + m) * 1024 + k0 + cA;
      async_copy16(&Ah[wid * 2048 + i * 512], Ahi + ao);
      async_copy16(&Al[wid * 2048 + i * 512], Alo + ao);
      int n = srow + i * 8;
      int cB = ((slot ^ (n & 7)) * 8);
      size_t bo = (size_t)(n0 + n) * 1024 + k0 + cB;
      async_copy16(&Bh[wid * 2048 + i * 512], Whi + bo);
      async_copy16(&Bl[wid * 2048 + i * 512], Wlo + bo);
    }
    __syncthreads();
    #pragma unroll
    for (int kk = 0; kk < 2; ++kk) {
      bf16x8 ah[4], al[4], bh[4], bl[4];
      #pragma unroll
      for (int i = 0; i < 4; ++i) {
        int mm = wm + i * 16 + (lane & 15);
        int sA = (kk * 4 + (lane >> 4)) ^ (mm & 7);
        ah[i] = *(const bf16x8*)&Ah[mm * 64 + sA * 8];
        al[i] = *(const bf16x8*)&Al[mm * 64 + sA * 8];
        int nn = wn + i * 16 + (lane & 15);
        int sB = (kk * 4 + (lane >> 4)) ^ (nn & 7);
        bh[i] = *(const bf16x8*)&Bh[nn * 64 + sB * 8];
        bl[i] = *(const bf16x8*)&Bl[nn * 64 + sB * 8];
      }
      #pragma unroll
      for (int i = 0; i < 4; ++i)
        #pragma unroll
        for (int j = 0; j < 4; ++j) {
          acc[i][j] = __builtin_amdgcn_mfma_f32_16x16x32_bf16(ah[i], bh[j], acc[i][j], 0, 0, 0);
          acc[i][j] = __builtin_amdgcn_mfma_f32_16x16x32_bf16(ah[i], bl[j], acc[i][j], 0, 0, 0);
          acc[i][j] = __builtin_amdgcn_mfma_f32_16x16x32_bf16(al[i], bh[j], acc[i][j], 0, 0, 0);
        }
    }
  }
  const int r0 = (lane >> 4) * 4, cc = lane & 15;
  #pragma unroll
  for (int i = 0; i < 4; ++i)
    #pragma unroll
    for (int j = 0; j < 4; ++j)
      #pragma unroll
      for (int r = 0; r < 4; ++r) {
        int m = m0 + wm + i * 16 + r0 + r;
        int n = n0 + wn + j * 16 + cc;
        Cout[(size_t)m * 1152 + n] = acc[i][j][r];
      }
}

// ---------------------------------------------------------------------------
// dt/a/gamma per (token, head); dt written back into projT col h.
__global__ __launch_bounds__(256) void dt_kernel(
    float* projT, const float* __restrict__ A_log, const float* __restrict__ dt_bias,
    float* __restrict__ a_buf, float* __restrict__ gamma_buf)
{
  const int idx = blockIdx.x * 256 + threadIdx.x;   // 0..262143
  const int t = idx >> 5, h = idx & 31;
  float dtr = projT[(size_t)t * 1152 + h] + dt_bias[h];
  float dt = softplus_f(dtr);
  float a = -expf(A_log[h]) * dt;
  float alpha = expf(a);
  float gamma = (alpha - 1.f) / (a + 1e-6f) * 0.5f + 1.f;
  projT[(size_t)t * 1152 + h] = dt;
  a_buf[idx] = a;
  gamma_buf[idx] = gamma;
}

// ---------------------------------------------------------------------------
// Proj GEMM, 256x256 tile, 8-phase counted-vmcnt schedule (HK/m201 template),
// with the fused per-region epilogue:
//   z[0,2048): plain bf16 store
//   x[2048,4096): xsum (row-sum over head) then *gamma
//   B[4096,6144): rmsnorm(row)*Bn_w + B_bias ; C[6144,8192): same w/ Cn_w
// See gemm256 below for the generic (schedule-identical) variant; this one
// keeps K=1024 compile-time constant + the fused epilogue.
__global__ __launch_bounds__(512, 2) void gemm_proj256(
    const bf16* __restrict__ A, const bf16* __restrict__ B, bf16* __restrict__ Cout,
    const float* __restrict__ gamma_buf, float* __restrict__ xsum,
    const float* __restrict__ Bn_w, const float* __restrict__ Cn_w,
    const float* __restrict__ B_bias, const float* __restrict__ C_bias)
{
  __shared__ bf16 lds[65536];          // 128 KiB: 8 half-slots x 8192 elems
  const int tid = threadIdx.x, wid = tid >> 6, lane = tid & 63;
  // T1: XCD-aware swizzle over 1024 blocks (1024 % 8 == 0 -> simple form ok)
  const int bid = blockIdx.x;
  const int swz = (bid & 7) * 128 + (bid >> 3);
  const int by = swz >> 5, bx = swz & 31;     // 32x32 tiles of 256
  const int m0 = by * 256, n0 = bx * 256;
  const int wr = wid >> 2, wc = wid & 3;      // wave -> (2M x 4N)
  const int fl = lane & 15, fq = lane >> 4;   // fragment lane coords
  const int rloc = wid * 8 + (lane >> 3);
  const int colSwz = ((lane & 7) ^ (lane >> 3)) * 8;

  fx4 acc[8][4];
  #pragma unroll
  for (int i = 0; i < 8; ++i)
    #pragma unroll
    for (int j = 0; j < 4; ++j) { fx4 z = {0.f, 0.f, 0.f, 0.f}; acc[i][j] = z; }

  const bf16* gA = A + (size_t)(m0 + rloc) * 1024 + colSwz;
  const bf16* gB = B + (size_t)(n0 + rloc) * 1024 + colSwz;

  // stage half h (0=B0,1=B1,2=A0,3=A1) of K-tile u; LDS slot = (4u+h) & 7.
  auto STAGE = [&](int u, int h) {
    const bf16* s = (h < 2) ? gB : gA;
    s += (size_t)(h & 1) * 128 * 1024 + u * 64;
    bf16* d = &lds[((u & 1) * 4 + h) * 8192 + wid * 512];   // wave-uniform
    async_copy16(d, s);
    async_copy16(d + 4096, s + 64 * 1024);
  };

  STAGE(0, 0); STAGE(0, 1); STAGE(0, 2); STAGE(0, 3);
  STAGE(1, 0); STAGE(1, 1);
  asm volatile("s_waitcnt vmcnt(4)" ::: "memory");
  __builtin_amdgcn_s_barrier();

  const int NT = 16;                    // K = 1024
  bf16x8 bfrag[4][2];
  for (int t = 0; t < NT; ++t) {
    const int Bb = (t & 1) * 32768;     // B-tile element base
    const int Ab = Bb + 16384;          // A-tile element base
    #pragma unroll
    for (int p = 0; p < 4; ++p) {
      bf16x8 af[2][2];
      if (p == 0) {
        #pragma unroll
        for (int j = 0; j < 4; ++j) {
          int nn = wc * 64 + j * 16 + fl;
          #pragma unroll
          for (int kk = 0; kk < 2; ++kk) {
            int q = (kk * 4 + fq) ^ (nn & 7);
            bfrag[j][kk] = *(const bf16x8*)&lds[Bb + nn * 64 + q * 8];
          }
        }
      }
      #pragma unroll
      for (int ii = 0; ii < 2; ++ii) {
        int mm = wr * 128 + (p * 2 + ii) * 16 + fl;
        #pragma unroll
        for (int kk = 0; kk < 2; ++kk) {
          int q = (kk * 4 + fq) ^ (mm & 7);
          af[ii][kk] = *(const bf16x8*)&lds[Ab + mm * 64 + q * 8];
        }
      }
      {
        int H = 4 * t + 6 + p;
        if (H < 4 * NT) STAGE(H >> 2, H & 3);
      }
      if (p == 3) asm volatile("s_waitcnt vmcnt(4)" ::: "memory");
      __builtin_amdgcn_s_barrier();
      asm volatile("s_waitcnt lgkmcnt(0)" ::: "memory");
      __builtin_amdgcn_sched_barrier(0);
      __builtin_amdgcn_s_setprio(1);
      #pragma unroll
      for (int ii = 0; ii < 2; ++ii)
        #pragma unroll
        for (int j = 0; j < 4; ++j)
          #pragma unroll
          for (int kk = 0; kk < 2; ++kk)
            acc[p * 2 + ii][j] = __builtin_amdgcn_mfma_f32_16x16x32_bf16(
                af[ii][kk], bfrag[j][kk], acc[p * 2 + ii][j], 0, 0, 0);
      __builtin_amdgcn_s_setprio(0);
      __builtin_amdgcn_s_barrier();
    }
  }

  // ---- fused epilogue ----
  const int reg = bx >> 3;                       // 0=z 1=x 2=B 3=C
  const int hh = ((n0 + wc * 64) & 2047) >> 6;   // head for this wave
  const int mwb = m0 + wr * 128;
  const int nwb = n0 + wc * 64;
  if (reg == 0) {
    #pragma unroll
    for (int i = 0; i < 8; ++i)
      #pragma unroll
      for (int j = 0; j < 4; ++j)
        #pragma unroll
        for (int r = 0; r < 4; ++r) {
          int m = mwb + i * 16 + fq * 4 + r;
          int n = nwb + j * 16 + fl;
          Cout[(size_t)m * 8192 + n] = (bf16)acc[i][j][r];
        }
  } else if (reg == 1) {
    #pragma unroll
    for (int i = 0; i < 8; ++i)
      #pragma unroll
      for (int r = 0; r < 4; ++r) {
        float s = acc[i][0][r] + acc[i][1][r] + acc[i][2][r] + acc[i][3][r];
        s = red16(s);
        int m = mwb + i * 16 + fq * 4 + r;
        if (fl == 0) xsum[(size_t)m * 32 + hh] = s;
        float g = gamma_buf[(size_t)m * 32 + hh];
        #pragma unroll
        for (int j = 0; j < 4; ++j) {
          int n = nwb + j * 16 + fl;
          Cout[(size_t)m * 8192 + n] = (bf16)(acc[i][j][r] * g);
        }
      }
  } else {
    const float* w = (reg == 2) ? Bn_w : Cn_w;
    const float* bias = (reg == 2) ? B_bias : C_bias;
    #pragma unroll
    for (int i = 0; i < 8; ++i)
      #pragma unroll
      for (int r = 0; r < 4; ++r) {
        float ss = acc[i][0][r] * acc[i][0][r] + acc[i][1][r] * acc[i][1][r]
                 + acc[i][2][r] * acc[i][2][r] + acc[i][3][r] * acc[i][3][r];
        ss = red16(ss);
        float sc = rsqrtf(ss * (1.f / 64.f) + 1e-5f);
        int m = mwb + i * 16 + fq * 4 + r;
        #pragma unroll
        for (int j = 0; j < 4; ++j) {
          int c = j * 16 + fl;
          Cout[(size_t)m * 8192 + nwb + c] =
              (bf16)(acc[i][j][r] * sc * w[c] + bias[hh * 64 + c]);
        }
      }
  }
}

// ---------------------------------------------------------------------------
// Generic 256x256-tile 8-phase GEMM (schedule identical to gemm_proj256,
// which is harness-verified; only epilogue + runtime geometry differ).
// C = A(MxK, lda) * B^T(NxK), MODE 1 = bf16 store, MODE 2 = f32 + resid.
// Requirements: M%256==0, N%256==0, K%64==0, grid%8==0 (bijective swizzle).
__global__ __launch_bounds__(512, 2) void gemm256_bf16(
    const bf16* __restrict__ A, const bf16* __restrict__ B, bf16* __restrict__ Cout,
    int NT, int lda, int ldc, int nbx)
{
  __shared__ bf16 lds[65536];
  const int tid = threadIdx.x, wid = tid >> 6, lane = tid & 63;
  const int cpx = gridDim.x >> 3;
  const int bid = blockIdx.x;
  const int swz = (bid & 7) * cpx + (bid >> 3);
  const int by = swz / nbx, bx = swz - by * nbx;
  const int m0 = by * 256, n0 = bx * 256;
  const int wr = wid >> 2, wc = wid & 3;
  const int fl = lane & 15, fq = lane >> 4;
  const int rloc = wid * 8 + (lane >> 3);
  const int colSwz = ((lane & 7) ^ (lane >> 3)) * 8;
  const int K = NT * 64;

  fx4 acc[8][4];
  #pragma unroll
  for (int i = 0; i < 8; ++i)
    #pragma unroll
    for (int j = 0; j < 4; ++j) { fx4 z = {0.f, 0.f, 0.f, 0.f}; acc[i][j] = z; }

  const bf16* gA = A + (size_t)(m0 + rloc) * lda + colSwz;
  const bf16* gB = B + (size_t)(n0 + rloc) * K + colSwz;

  auto STAGE = [&](int u, int h) {
    const bf16* s = (h < 2) ? gB : gA;
    const size_t str = (h < 2) ? (size_t)K : (size_t)lda;
    s += (size_t)(h & 1) * 128 * str + u * 64;
    bf16* d = &lds[((u & 1) * 4 + h) * 8192 + wid * 512];
    async_copy16(d, s);
    async_copy16(d + 4096, s + 64 * str);
  };

  STAGE(0, 0); STAGE(0, 1); STAGE(0, 2); STAGE(0, 3);
  STAGE(1, 0); STAGE(1, 1);
  asm volatile("s_waitcnt vmcnt(4)" ::: "memory");
  __builtin_amdgcn_s_barrier();

  bf16x8 bfrag[4][2];
  for (int t = 0; t < NT; ++t) {
    const int Bb = (t & 1) * 32768;
    const int Ab = Bb + 16384;
    #pragma unroll
    for (int p = 0; p < 4; ++p) {
      bf16x8 af[2][2];
      if (p == 0) {
        #pragma unroll
        for (int j = 0; j < 4; ++j) {
          int nn = wc * 64 + j * 16 + fl;
          #pragma unroll
          for (int kk = 0; kk < 2; ++kk) {
            int q = (kk * 4 + fq) ^ (nn & 7);
            bfrag[j][kk] = *(const bf16x8*)&lds[Bb + nn * 64 + q * 8];
          }
        }
      }
      #pragma unroll
      for (int ii = 0; ii < 2; ++ii) {
        int mm = wr * 128 + (p * 2 + ii) * 16 + fl;
        #pragma unroll
        for (int kk = 0; kk < 2; ++kk) {
          int q = (kk * 4 + fq) ^ (mm & 7);
          af[ii][kk] = *(const bf16x8*)&lds[Ab + mm * 64 + q * 8];
        }
      }
      {
        int H = 4 * t + 6 + p;
        if (H < 4 * NT) STAGE(H >> 2, H & 3);
      }
      if (p == 3) asm volatile("s_waitcnt vmcnt(4)" ::: "memory");
      __builtin_amdgcn_s_barrier();
      asm volatile("s_waitcnt lgkmcnt(0)" ::: "memory");
      __builtin_amdgcn_sched_barrier(0);
      __builtin_amdgcn_s_setprio(1);
      #pragma unroll
      for (int ii = 0; ii < 2; ++ii)
        #pragma unroll
        for (int j = 0; j < 4; ++j)
          #pragma unroll
          for (int kk = 0; kk < 2; ++kk)
            acc[p * 2 + ii][j] = __builtin_amdgcn_mfma_f32_16x16x32_bf16(
                af[ii][kk], bfrag[j][kk], acc[p * 2 + ii][j], 0, 0, 0);
      __builtin_amdgcn_s_setprio(0);
      __builtin_amdgcn_s_barrier();
    }
  }

  const int mwb = m0 + wr * 128;
  const int nwb = n0 + wc * 64;
  #pragma unroll
  for (int i = 0; i < 8; ++i)
    #pragma unroll
    for (int j = 0; j < 4; ++j)
      #pragma unroll
      for (int r = 0; r < 4; ++r) {
        int m = mwb + i * 16 + fq * 4 + r;
        int n = nwb + j * 16 + fl;
        Cout[(size_t)m * ldc + n] = (bf16)acc[i][j][r];
      }
}

// ---------------------------------------------------------------------------
// Chunk sums of dt*theta: S[(b*64+c)][h*32+d], head-quartered grid (128,4).
__global__ __launch_bounds__(256) void chunk_sum_kernel(
    const float* __restrict__ projT, float* __restrict__ S)
{
  __shared__ float lds[8 * 288];   // 8 rows x (32 dt + 256 theta)
  const int blk = blockIdx.x;      // b*64 + c
  const int hq = blockIdx.y;       // head quarter
  const size_t row0 = (size_t)blk * 64;
  const int tid = threadIdx.x;
  float s = 0.f;
  #pragma unroll 1
  for (int batch = 0; batch < 8; ++batch) {
    __syncthreads();
    const float* src = projT + (row0 + batch * 8) * 1152;
    #pragma unroll
    for (int i = 0; i < 9; ++i) {
      int idx = i * 256 + tid;
      int r = idx / 288, col = idx - r * 288;
      int gcol = (col < 32) ? col : (32 + hq * 256 + (col - 32));
      lds[idx] = src[r * 1152 + gcol];
    }
    __syncthreads();
    int hl = tid >> 5, d = tid & 31;
    #pragma unroll
    for (int r = 0; r < 8; ++r)
      s += lds[r * 288 + hq * 8 + hl] * lds[r * 288 + 32 + hl * 32 + d];
  }
  S[(size_t)blk * 1024 + hq * 256 + tid] = s;
}

// ---------------------------------------------------------------------------
// RoPE apply, one block per (b,c,h).
__global__ __launch_bounds__(256) void rope_kernel(
    bf16* proj, const float* __restrict__ projT, const float* __restrict__ S)
{
  __shared__ float angs[64 * 33], angc[64 * 33];
  const int blk = blockIdx.x;
  const int b = blk >> 11, c = (blk >> 5) & 63, h = blk & 31;
  const size_t t0 = (size_t)b * 4096 + c * 64;
  const int w = threadIdx.x >> 6, lane = threadIdx.x & 63;
  const float* tr = projT + (t0 + lane) * 1152;
  float dtv = tr[h];
  const float* thp = tr + 32 + h * 32 + w * 8;
  float4 th0 = *(const float4*)thp;
  float4 th1 = *(const float4*)(thp + 4);
  const float* Sp = S + (size_t)(b * 64 + lane) * 1024 + h * 32 + w * 8;
  float4 S0 = *(const float4*)Sp;
  float4 S1 = *(const float4*)(Sp + 4);
  float th[8] = { th0.x, th0.y, th0.z, th0.w, th1.x, th1.y, th1.z, th1.w };
  float Sv[8] = { S0.x, S0.y, S0.z, S0.w, S1.x, S1.y, S1.z, S1.w };
  #pragma unroll 1
  for (int j = 0; j < 8; ++j) {
    int d = w * 8 + j;
    float sv = (lane < c) ? Sv[j] : 0.f;
    float off = warp_sum64(sv);
    float v = dtv * th[j];
    #pragma unroll
    for (int o = 1; o < 64; o <<= 1) { float u = __shfl_up(v, o); if (lane >= o) v += u; }
    float ang = off + v;
    float sn, cs;
    sincosf(ang, &sn, &cs);
    angs[lane * 33 + d] = sn;
    angc[lane * 33 + d] = cs;
  }
  __syncthreads();
  const int tt = threadIdx.x >> 2, q = threadIdx.x & 3;
  const size_t base = (t0 + tt) * 8192 + 4096 + h * 64 + q * 16;
  #pragma unroll
  for (int m = 0; m < 2; ++m) {   // m=0: B, m=1: C
    bf16* p = proj + base + m * 2048;
    bf16x8 v0 = *(const bf16x8*)(p);
    bf16x8 v1 = *(const bf16x8*)(p + 8);
    bf16x8 r0, r1;
    #pragma unroll
    for (int pp = 0; pp < 4; ++pp) {
      int d = q * 8 + pp;
      float e1 = (float)v0[2 * pp], e2 = (float)v0[2 * pp + 1];
      float sn = angs[tt * 33 + d], cs = angc[tt * 33 + d];
      r0[2 * pp]     = (bf16)(cs * e1 - sn * e2);
      r0[2 * pp + 1] = (bf16)(sn * e1 + cs * e2);
    }
    #pragma unroll
    for (int pp = 0; pp < 4; ++pp) {
      int d = q * 8 + 4 + pp;
      float e1 = (float)v1[2 * pp], e2 = (float)v1[2 * pp + 1];
      float sn = angs[tt * 33 + d], cs = angc[tt * 33 + d];
      r1[2 * pp]     = (bf16)(cs * e1 - sn * e2);
      r1[2 * pp + 1] = (bf16)(sn * e1 + cs * e2);
    }
    *(bf16x8*)(p) = r0;
    *(bf16x8*)(p + 8) = r1;
  }
}

// ---------------------------------------------------------------------------
// SSD stage 1 (MFMA), one block per (b,c,h) with blk = b*2048+c*32+h.
__global__ __launch_bounds__(256) void ssd1_kernel(
    const bf16* __restrict__ proj, const float* __restrict__ a_buf,
    bf16* __restrict__ Bx, bf16* __restrict__ states,
    float* __restrict__ rowsum, float* __restrict__ expac, float* __restrict__ dchunk)
{
  __shared__ bf16 Xs[64 * 72], Bs[64 * 72];
  __shared__ float acum[64], dsv[64];
  const int blk = blockIdx.x;
  const int h = blk & 31;
  const size_t bs0 = ((size_t)(blk >> 5)) * 64;
  const int tid = threadIdx.x;
  const int l = tid >> 2, p0 = (tid & 3) * 16;
  {
    const bf16* xrow = proj + (bs0 + l) * 8192 + 2048 + h * 64 + p0;
    *(bf16x8*)&Xs[l * 72 + p0]     = ((const bf16x8*)xrow)[0];
    *(bf16x8*)&Xs[l * 72 + p0 + 8] = ((const bf16x8*)xrow)[1];
    const bf16* brow = proj + (bs0 + l) * 8192 + 4096 + h * 64 + p0;
    *(bf16x8*)&Bs[l * 72 + p0]     = ((const bf16x8*)brow)[0];
    *(bf16x8*)&Bs[l * 72 + p0 + 8] = ((const bf16x8*)brow)[1];
  }
  if (tid < 64) {
    float v = a_buf[(bs0 + tid) * 32 + h];
    #pragma unroll
    for (int o = 1; o < 64; o <<= 1) { float u = __shfl_up(v, o); if (tid >= o) v += u; }
    acum[tid] = v;
    float a63 = __shfl(v, 63);
    dsv[tid] = expf(a63 - v);
    expac[(size_t)blk * 64 + tid] = expf(v);
    if (tid == 63) dchunk[blk] = expf(v);
  }
  __syncthreads();
  {
    float al = acum[l];
    float rs = 0.f;
    for (int s = tid & 3; s <= l; s += 4) rs += expf(al - acum[s]);
    rs += __shfl_xor(rs, 1);
    rs += __shfl_xor(rs, 2);
    if ((tid & 3) == 0) rowsum[(size_t)blk * 64 + l] = rs + (float)(63 - l);
  }
  const int wv = tid >> 6, lane = tid & 63;
  const int mi = lane & 15, kq = lane >> 4;
  const int m0 = wv * 16;
  fx4 accB[4], accS[4];
  #pragma unroll
  for (int j4 = 0; j4 < 4; ++j4) { fx4 z = {0.f,0.f,0.f,0.f}; accB[j4] = z; accS[j4] = z; }
  #pragma unroll
  for (int kk = 0; kk < 2; ++kk) {
    const int lb = kk * 32 + kq * 8;
    bf16x8 aX, aXd;
    #pragma unroll
    for (int j = 0; j < 8; ++j) {
      bf16 xv = Xs[(lb + j) * 72 + m0 + mi];
      aX[j] = xv;
      aXd[j] = (bf16)((float)xv * dsv[lb + j]);
    }
    #pragma unroll
    for (int j4 = 0; j4 < 4; ++j4) {
      bf16x8 bB;
      #pragma unroll
      for (int j = 0; j < 8; ++j) bB[j] = Bs[(lb + j) * 72 + j4 * 16 + mi];
      accB[j4] = __builtin_amdgcn_mfma_f32_16x16x32_bf16(aX, bB, accB[j4], 0, 0, 0);
      accS[j4] = __builtin_amdgcn_mfma_f32_16x16x32_bf16(aXd, bB, accS[j4], 0, 0, 0);
    }
  }
  const size_t obase = (size_t)blk * 4096;
  #pragma unroll
  for (int j4 = 0; j4 < 4; ++j4) {
    #pragma unroll
    for (int r = 0; r < 4; ++r) {
      int p = m0 + kq * 4 + r;
      int n = j4 * 16 + mi;
      Bx[obase + p * 64 + n] = (bf16)accB[j4][r];
      states[obase + p * 64 + n] = (bf16)accS[j4][r];
    }
  }
}

// ---------------------------------------------------------------------------
// SSD stage 2: inclusive scan over chunks (f32 carry, bf16 storage).
__global__ __launch_bounds__(128) void ssd2_kernel(
    bf16* __restrict__ states, const float* __restrict__ dchunk)
{
  const int blk = blockIdx.x;  // 1024 = b(2) x h(32) x q(16)
  const int b = blk >> 9, rest = blk & 511;
  const int h = rest >> 4, q = rest & 15;
  const int e0 = q * 256 + threadIdx.x * 2;
  float fs0 = 0.f, fs1 = 0.f;
  #pragma unroll 2
  for (int c = 0; c < 64; ++c) {
    size_t idx = ((size_t)(b * 2048 + c * 32 + h) * 4096) + e0;
    float dec = dchunk[b * 2048 + c * 32 + h];
    bf16x2 st = *(const bf16x2*)(states + idx);
    fs0 = fs0 * dec + (float)st[0];
    fs1 = fs1 * dec + (float)st[1];
    bf16x2 o = { (bf16)fs0, (bf16)fs1 };
    *(bf16x2*)(states + idx) = o;
  }
}

// ---------------------------------------------------------------------------
// SSD stage 3 (MFMA), one block per (b,c,h).
__global__ __launch_bounds__(256) void ssd3_kernel(
    bf16* proj, const bf16* __restrict__ Bx, const bf16* __restrict__ FS,
    const float* __restrict__ rowsum, const float* __restrict__ expac,
    const float* __restrict__ xsum, const float* __restrict__ D_param)
{
  __shared__ bf16 Cs[64 * 72], BxS[64 * 72], FSs[64 * 72];
  __shared__ float rs_s[64], ea_s[64], sk_s[64];
  const int blk = blockIdx.x;
  const int h = blk & 31;
  const size_t bs0 = ((size_t)(blk >> 5)) * 64;
  const int tid = threadIdx.x;
  const int l = tid >> 2, q0 = (tid & 3) * 16;
  {
    const bf16* crow = proj + (bs0 + l) * 8192 + 6144 + h * 64 + q0;
    *(bf16x8*)&Cs[l * 72 + q0]     = ((const bf16x8*)crow)[0];
    *(bf16x8*)&Cs[l * 72 + q0 + 8] = ((const bf16x8*)crow)[1];
    size_t mb = (size_t)blk * 4096 + l * 64 + q0;
    *(bf16x8*)&BxS[l * 72 + q0]     = ((const bf16x8*)(Bx + mb))[0];
    *(bf16x8*)&BxS[l * 72 + q0 + 8] = ((const bf16x8*)(Bx + mb))[1];
    *(bf16x8*)&FSs[l * 72 + q0]     = ((const bf16x8*)(FS + mb))[0];
    *(bf16x8*)&FSs[l * 72 + q0 + 8] = ((const bf16x8*)(FS + mb))[1];
  }
  if (tid < 64) {
    rs_s[tid] = rowsum[(size_t)blk * 64 + tid];
    ea_s[tid] = expac[(size_t)blk * 64 + tid];
    sk_s[tid] = D_param[h] * xsum[(bs0 + tid) * 32 + h];
  }
  __syncthreads();
  const int wv = tid >> 6, lane = tid & 63;
  const int mi = lane & 15, kq = lane >> 4;
  const int m0 = wv * 16;
  fx4 acc1[4], acc2[4];
  #pragma unroll
  for (int j4 = 0; j4 < 4; ++j4) { fx4 z = {0.f,0.f,0.f,0.f}; acc1[j4] = z; acc2[j4] = z; }
  #pragma unroll
  for (int kk = 0; kk < 2; ++kk) {
    bf16x8 aC = *(const bf16x8*)&Cs[(m0 + mi) * 72 + kk * 32 + kq * 8];
    #pragma unroll
    for (int j4 = 0; j4 < 4; ++j4) {
      bf16x8 bx = *(const bf16x8*)&BxS[(j4 * 16 + mi) * 72 + kk * 32 + kq * 8];
      bf16x8 fs = *(const bf16x8*)&FSs[(j4 * 16 + mi) * 72 + kk * 32 + kq * 8];
      acc1[j4] = __builtin_amdgcn_mfma_f32_16x16x32_bf16(aC, bx, acc1[j4], 0, 0, 0);
      acc2[j4] = __builtin_amdgcn_mfma_f32_16x16x32_bf16(aC, fs, acc2[j4], 0, 0, 0);
    }
  }
  #pragma unroll
  for (int j4 = 0; j4 < 4; ++j4) {
    #pragma unroll
    for (int r = 0; r < 4; ++r) {
      int li = m0 + kq * 4 + r;
      int p = j4 * 16 + mi;
      float y = rs_s[li] * acc1[j4][r] + ea_s[li] * acc2[j4][r] + sk_s[li];
      size_t zoff = (bs0 + li) * 8192 + h * 64 + p;
      float z = (float)proj[zoff];
      proj[zoff + 2048] = (bf16)(y * z * sigmoid_f(z));
    }
  }
}

// ---------------------------------------------------------------------------
__global__ __launch_bounds__(256) void silu_mul_kernel(
    const bf16* __restrict__ gu, bf16* __restrict__ m)
{
  const size_t row = blockIdx.y;
  const int col2 = blockIdx.x * 256 + threadIdx.x;  // 0..1279
  const size_t gi = row * 5120 + col2 * 2;
  bf16x2 g = *(const bf16x2*)(gu + gi);
  bf16x2 u = *(const bf16x2*)(gu + gi + 2560);
  float g0 = (float)g[0], g1 = (float)g[1];
  float m0 = g0 * sigmoid_f(g0) * (float)u[0];
  float m1 = g1 * sigmoid_f(g1) * (float)u[1];
  bf16x2 mv = { (bf16)m0, (bf16)m1 };
  *(bf16x2*)(m + row * 2560 + col2 * 2) = mv;
}

// ---------------------------------------------------------------------------
extern "C" void kernel_launch(void* const* d_in, const int* in_sizes, int n_in,
                              void* d_out, int out_size, void* d_ws, size_t ws_size,
                              hipStream_t stream) {
  (void)in_sizes; (void)n_in; (void)out_size;
  if (ws_size < WS_NEEDED) return;  // diagnostic guard: fail absmax, not SIGABRT
  const float* x       = (const float*)d_in[0];
  const float* n1w     = (const float*)d_in[1];
  const float* n2w     = (const float*)d_in[2];
  const float* W_in    = (const float*)d_in[3];
  const float* W_out   = (const float*)d_in[4];
  const float* A_log   = (const float*)d_in[5];
  const float* D_param = (const float*)d_in[6];
  const float* dt_bias = (const float*)d_in[7];
  const float* B_bias  = (const float*)d_in[8];
  const float* C_bias  = (const float*)d_in[9];
  const float* Bn_w    = (const float*)d_in[10];
  const float* Cn_w    = (const float*)d_in[11];
  const float* Wg      = (const float*)d_in[12];
  const float* Wu      = (const float*)d_in[13];
  const float* Wd      = (const float*)d_in[14];
  float* out = (float*)d_out;
  char* ws = (char*)d_ws;

  bf16*  proj   = (bf16*)(ws + OFF_PROJ);
  float* projT  = (float*)(ws + OFF_PROJT);
  bf16*  h_hi   = (bf16*)(ws + OFF_HHI);
  bf16*  h_lo   = (bf16*)(ws + OFF_HLO);
  bf16*  Wt_in  = (bf16*)(ws + OFF_WTIN);
  bf16*  Wt_hi  = (bf16*)(ws + OFF_WTHI);
  bf16*  Wt_lo  = (bf16*)(ws + OFF_WTLO);
  bf16*  Wt_out = (bf16*)(ws + OFF_WTOUT);
  bf16*  Wt_gu  = (bf16*)(ws + OFF_WTGU);
  bf16*  Wt_d   = (bf16*)(ws + OFF_WTD);
  bf16*  Bx     = (bf16*)(ws + OFF_BX);
  bf16*  states = (bf16*)(ws + OFF_STATES);
  float* a_buf  = (float*)(ws + OFF_ABUF);
  float* xsum_  = (float*)(ws + OFF_XSUM);
  float* rowsum = (float*)(ws + OFF_ROWSUM);
  float* expac  = (float*)(ws + OFF_EXPA);
  float* dchunk = (float*)(ws + OFF_DCHUNK);
  float* gamma_ = (float*)(ws + OFF_GAMMA);
  float* Ssum   = (float*)(ws + OFF_HLO);    // 512KB chunk sums (h_lo dead by then)
  bf16*  ybf    = proj + 2048;               // cols [2048,4096) of proj, lda 8192
  bf16*  gubf   = (bf16*)(ws + OFF_GU);
  bf16*  mbf    = (bf16*)(ws + OFF_MBF);
  bf16*  h2bf   = h_hi;                      // reuse after proj GEMMs
  float* x2     = out;                       // x2 lives in d_out

  // --- weight transposes needed up-front ---
  transpose_cast<<<dim3(256, 32), 256, 0, stream>>>(W_in, 9248, 0, Wt_in, 1024, 8192);
  transpose_cast_hilo<<<dim3(36, 32), 256, 0, stream>>>(W_in, 9248, 8192, Wt_hi, Wt_lo, 1024, 1056);

  // --- norm1 (hi/lo split for the precision-critical dt/theta tail GEMM) ---
  rmsnorm_kernel<<<8192, 256, 0, stream>>>(x, n1w, h_hi, h_lo);

  // --- in-projection: fused hi/lo tail, then dt, then proj w/ fused prep ---
  gemm_tail<<<dim3(9, 64), 256, 0, stream>>>(h_hi, h_lo, Wt_hi, Wt_lo, projT);
  dt_kernel<<<1024, 256, 0, stream>>>(projT, A_log, dt_bias, a_buf, gamma_);
  gemm_proj256<<<dim3(1024), 512, 0, stream>>>(h_hi, Wt_in, proj, gamma_, xsum_,
                                               Bn_w, Cn_w, B_bias, C_bias);

  // --- hierarchical RoPE ---
  chunk_sum_kernel<<<dim3(128, 4), 256, 0, stream>>>(projT, Ssum);
  rope_kernel<<<4096, 256, 0, stream>>>(proj, projT, Ssum);

  // --- SSD (MFMA) ---
  ssd1_kernel<<<4096, 256, 0, stream>>>(proj, a_buf, Bx, states, rowsum, expac, dchunk);
  ssd2_kernel<<<1024, 128, 0, stream>>>(states, dchunk);
  ssd3_kernel<<<4096, 256, 0, stream>>>(proj, Bx, states, rowsum, expac, xsum_, D_param);

  // --- late weight transposes (overlay dead states region) ---
  transpose_cast<<<dim3(32, 64), 256, 0, stream>>>(W_out, 1024, 0, Wt_out, 2048, 1024);
  transpose_cast<<<dim3(80, 32), 256, 0, stream>>>(Wg, 2560, 0, Wt_gu, 1024, 2560);
  transpose_cast<<<dim3(80, 32), 256, 0, stream>>>(Wu, 2560, 0, Wt_gu + (size_t)2560 * 1024, 1024, 2560);
  transpose_cast<<<dim3(32, 80), 256, 0, stream>>>(Wd, 1024, 0, Wt_d, 2560, 1024);

  // --- out-projection + residual (x2 -> d_out) ---
  gemm_bt<2><<<dim3(8, 64), 256, 0, stream>>>(ybf, Wt_out, x2, x, 2048, 8192, 1024);

  // --- MLP ---
  rmsnorm_kernel<<<8192, 256, 0, stream>>>(x2, n2w, h2bf, nullptr);
  // gu GEMM on the verified 256^2 8-phase schedule: M=8192, N=5120, K=1024.
  // Grid 32x20 = 640 blocks (640 % 8 == 0 -> bijective XCD swizzle).
  gemm256_bf16<<<dim3(640), 512, 0, stream>>>(h2bf, Wt_gu, gubf, 16, 1024, 5120, 20);
  silu_mul_kernel<<<dim3(5, 8192), 256, 0, stream>>>(gubf, mbf);
  gemm_bt<2><<<dim3(8, 64), 256, 0, stream>>>(mbf, Wt_d, out, x2, 2560, 2560, 1024);
}

// Round 3
// 782.968 us; speedup vs baseline: 1.0623x; 1.0623x over previous
//
#include <hip/hip_runtime.h>
#include <cstdint>
#include <cmath>

// ---------------------------------------------------------------------------
// Mamba3 block forward, MI355X (gfx950).
// B=2, S=4096 (8192 tokens), D_MODEL=1024, D_INNER=2048, NHEADS=32, HD=64,
// D_STATE=64, CHUNK=64, D_MLP=2560, PROJ=9248.
// Workspace budget: ~251.5 MiB. x2 lives in d_out.
//
// R1: gemm_proj -> 256^2 8-phase counted-vmcnt schedule: 207 -> 162 us.
// R2: gu on 256^2 tiles REGRESSED (+19 us): 640 blocks = 2.5 rounds at
//     1 blk/CU -> 3 effective rounds, grid quantization ate the gain.
// R3: BM=128 x BN=256 variant of the same 8-phase schedule (6-slot ring,
//     96KB LDS, vmcnt(4)) -> exact-round grids for gu (1280 = 5 rounds),
//     out (256 = 1 round), down (256 = 1 round). gemm_bt/gemm256 removed.
// ---------------------------------------------------------------------------

typedef __bf16 bf16;
typedef __bf16 bf16x2 __attribute__((ext_vector_type(2)));
typedef __bf16 bf16x4 __attribute__((ext_vector_type(4)));
typedef __bf16 bf16x8 __attribute__((ext_vector_type(8)));
typedef float fx4 __attribute__((ext_vector_type(4)));

#define DEV __device__ __forceinline__

// ---- workspace layout (bytes) ---------------------------------------------
#define OFF_PROJ    0ull
#define OFF_HHI     134217728ull   // 8192x1024 bf16 (h hi) ; later h2_bf
#define OFF_HLO     150994944ull   // 8192x1024 bf16 (h lo) ; later S (chunk sums, 512KB)
#define OFF_WTIN    167772160ull   // 8192x1024 bf16
#define OFF_WTHI    184549376ull   // 1152x1024 bf16
#define OFF_WTLO    186908672ull   // 1152x1024 bf16
#define OFF_PROJT   189267968ull   // 8192x1152 f32 (dt,theta) -- dead after rope
#define OFF_BX      189267968ull   // 4096x4096 bf16 (written at ssd1, overlays projT)
#define OFF_STATES  222822400ull   // 4096x4096 bf16 -> FS in place; dead after ssd3
#define OFF_WTOUT   222822400ull   // 1024x2048 bf16 (after ssd3, overlays states)
#define OFF_WTGU    227016704ull   // 5120x1024 bf16 (after ssd3)
#define OFF_WTD     237502464ull   // 1024x2560 bf16 (after ssd3)
#define OFF_ABUF    256376832ull   // 8192x32 f32 (per-token A)
#define OFF_XSUM    257425408ull   // 8192x32 f32
#define OFF_ROWSUM  258473984ull   // (2,64,32,64) f32
#define OFF_EXPA    260571136ull   // (2,64,32,64) f32
#define OFF_DCHUNK  262668288ull   // (2,64,32) f32
#define OFF_GAMMA   262684672ull   // 8192x32 f32
#define WS_NEEDED   263733248ull

#define OFF_GU      0ull
#define OFF_MBF     83886080ull

// ---------------------------------------------------------------------------
DEV void async_copy16(void* lds, const void* gptr) {
  __builtin_amdgcn_global_load_lds(
      (const __attribute__((address_space(1))) unsigned int*)(gptr),
      (__attribute__((address_space(3))) unsigned int*)(lds),
      16, 0, 0);
}

DEV float warp_sum64(float v) {
  #pragma unroll
  for (int o = 32; o; o >>= 1) v += __shfl_xor(v, o);
  return v;
}

DEV float red16(float v) {   // reduce across 16-lane groups (cc dimension)
  v += __shfl_xor(v, 1); v += __shfl_xor(v, 2);
  v += __shfl_xor(v, 4); v += __shfl_xor(v, 8);
  return v;
}

DEV float softplus_f(float x) { return x > 20.f ? x : log1pf(expf(x)); }
DEV float sigmoid_f(float x) { return 1.f / (1.f + expf(-x)); }

// ---------------------------------------------------------------------------
__global__ __launch_bounds__(256) void transpose_cast(
    const float* __restrict__ src, int ld, int col0,
    bf16* __restrict__ dst, int R, int C)
{
  __shared__ float tile[32][33];
  const int c0 = blockIdx.x * 32, r0 = blockIdx.y * 32;
  const int tx = threadIdx.x & 31, ty = threadIdx.x >> 5;
  #pragma unroll
  for (int ii = 0; ii < 4; ++ii) {
    int i = ty + ii * 8;
    int c = c0 + tx;
    tile[i][tx] = (c < C) ? src[(size_t)(r0 + i) * ld + col0 + c] : 0.f;
  }
  __syncthreads();
  #pragma unroll
  for (int ii = 0; ii < 4; ++ii) {
    int i = ty + ii * 8;
    dst[(size_t)(c0 + i) * R + r0 + tx] = (bf16)tile[tx][i];
  }
}

__global__ __launch_bounds__(256) void transpose_cast_hilo(
    const float* __restrict__ src, int ld, int col0,
    bf16* __restrict__ dhi, bf16* __restrict__ dlo, int R, int C)
{
  __shared__ float tile[32][33];
  const int c0 = blockIdx.x * 32, r0 = blockIdx.y * 32;
  const int tx = threadIdx.x & 31, ty = threadIdx.x >> 5;
  #pragma unroll
  for (int ii = 0; ii < 4; ++ii) {
    int i = ty + ii * 8;
    int c = c0 + tx;
    tile[i][tx] = (c < C) ? src[(size_t)(r0 + i) * ld + col0 + c] : 0.f;
  }
  __syncthreads();
  #pragma unroll
  for (int ii = 0; ii < 4; ++ii) {
    int i = ty + ii * 8;
    float v = tile[tx][i];
    bf16 hi = (bf16)v;
    size_t o = (size_t)(c0 + i) * R + r0 + tx;
    dhi[o] = hi;
    dlo[o] = (bf16)(v - (float)hi);
  }
}

// ---------------------------------------------------------------------------
__global__ __launch_bounds__(256) void rmsnorm_kernel(
    const float* __restrict__ x, const float* __restrict__ w,
    bf16* __restrict__ hi, bf16* __restrict__ lo)
{
  __shared__ float red[4];
  const size_t row = blockIdx.x;
  const int tid = threadIdx.x;
  float4 v = ((const float4*)(x + row * 1024))[tid];
  float ss = v.x * v.x + v.y * v.y + v.z * v.z + v.w * v.w;
  ss = warp_sum64(ss);
  if ((tid & 63) == 0) red[tid >> 6] = ss;
  __syncthreads();
  float tot = red[0] + red[1] + red[2] + red[3];
  float s = rsqrtf(tot * (1.f / 1024.f) + 1e-5f);
  float4 wv = ((const float4*)w)[tid];
  float h0 = v.x * s * wv.x, h1 = v.y * s * wv.y, h2 = v.z * s * wv.z, h3 = v.w * s * wv.w;
  bf16x4 hv = { (bf16)h0, (bf16)h1, (bf16)h2, (bf16)h3 };
  *(bf16x4*)(hi + row * 1024 + tid * 4) = hv;
  if (lo) {
    bf16x4 lv = { (bf16)(h0 - (float)hv[0]), (bf16)(h1 - (float)hv[1]),
                  (bf16)(h2 - (float)hv[2]), (bf16)(h3 - (float)hv[3]) };
    *(bf16x4*)(lo + row * 1024 + tid * 4) = lv;
  }
}

// ---------------------------------------------------------------------------
// Fused hi/lo tail GEMM: out = Ahi*Whi^T + Ahi*Wlo^T + Alo*Whi^T (f32 out).
// M=8192, N=1152, K=1024, ldc=1152. 64KB LDS (4 tiles).
__global__ __launch_bounds__(256) void gemm_tail(
    const bf16* Ahi, const bf16* Alo, const bf16* Whi, const bf16* Wlo,
    float* Cout)
{
  __shared__ bf16 Ah[128 * 64], Al[128 * 64], Bh[128 * 64], Bl[128 * 64];
  const int tid = threadIdx.x, wid = tid >> 6, lane = tid & 63;
  const int m0 = blockIdx.y * 128, n0 = blockIdx.x * 128;
  const int wm = (wid & 1) * 64, wn = (wid >> 1) * 64;
  fx4 acc[4][4];
  #pragma unroll
  for (int i = 0; i < 4; ++i)
    #pragma unroll
    for (int j = 0; j < 4; ++j) { fx4 z = {0.f, 0.f, 0.f, 0.f}; acc[i][j] = z; }

  const int srow = wid * 32 + (lane >> 3);
  const int slot = lane & 7;

  for (int k0 = 0; k0 < 1024; k0 += 64) {
    __syncthreads();
    #pragma unroll
    for (int i = 0; i < 4; ++i) {
      int m = srow + i * 8;
      int cA = ((slot ^ (m & 7)) * 8);
      size_t ao = (size_t)(m0 + m) * 1024 + k0 + cA;
      async_copy16(&Ah[wid * 2048 + i * 512], Ahi + ao);
      async_copy16(&Al[wid * 2048 + i * 512], Alo + ao);
      int n = srow + i * 8;
      int cB = ((slot ^ (n & 7)) * 8);
      size_t bo = (size_t)(n0 + n) * 1024 + k0 + cB;
      async_copy16(&Bh[wid * 2048 + i * 512], Whi + bo);
      async_copy16(&Bl[wid * 2048 + i * 512], Wlo + bo);
    }
    __syncthreads();
    #pragma unroll
    for (int kk = 0; kk < 2; ++kk) {
      bf16x8 ah[4], al[4], bh[4], bl[4];
      #pragma unroll
      for (int i = 0; i < 4; ++i) {
        int mm = wm + i * 16 + (lane & 15);
        int sA = (kk * 4 + (lane >> 4)) ^ (mm & 7);
        ah[i] = *(const bf16x8*)&Ah[mm * 64 + sA * 8];
        al[i] = *(const bf16x8*)&Al[mm * 64 + sA * 8];
        int nn = wn + i * 16 + (lane & 15);
        int sB = (kk * 4 + (lane >> 4)) ^ (nn & 7);
        bh[i] = *(const bf16x8*)&Bh[nn * 64 + sB * 8];
        bl[i] = *(const bf16x8*)&Bl[nn * 64 + sB * 8];
      }
      #pragma unroll
      for (int i = 0; i < 4; ++i)
        #pragma unroll
        for (int j = 0; j < 4; ++j) {
          acc[i][j] = __builtin_amdgcn_mfma_f32_16x16x32_bf16(ah[i], bh[j], acc[i][j], 0, 0, 0);
          acc[i][j] = __builtin_amdgcn_mfma_f32_16x16x32_bf16(ah[i], bl[j], acc[i][j], 0, 0, 0);
          acc[i][j] = __builtin_amdgcn_mfma_f32_16x16x32_bf16(al[i], bh[j], acc[i][j], 0, 0, 0);
        }
    }
  }
  const int r0 = (lane >> 4) * 4, cc = lane & 15;
  #pragma unroll
  for (int i = 0; i < 4; ++i)
    #pragma unroll
    for (int j = 0; j < 4; ++j)
      #pragma unroll
      for (int r = 0; r < 4; ++r) {
        int m = m0 + wm + i * 16 + r0 + r;
        int n = n0 + wn + j * 16 + cc;
        Cout[(size_t)m * 1152 + n] = acc[i][j][r];
      }
}

// ---------------------------------------------------------------------------
// dt/a/gamma per (token, head); dt written back into projT col h.
__global__ __launch_bounds__(256) void dt_kernel(
    float* projT, const float* __restrict__ A_log, const float* __restrict__ dt_bias,
    float* __restrict__ a_buf, float* __restrict__ gamma_buf)
{
  const int idx = blockIdx.x * 256 + threadIdx.x;   // 0..262143
  const int t = idx >> 5, h = idx & 31;
  float dtr = projT[(size_t)t * 1152 + h] + dt_bias[h];
  float dt = softplus_f(dtr);
  float a = -expf(A_log[h]) * dt;
  float alpha = expf(a);
  float gamma = (alpha - 1.f) / (a + 1e-6f) * 0.5f + 1.f;
  projT[(size_t)t * 1152 + h] = dt;
  a_buf[idx] = a;
  gamma_buf[idx] = gamma;
}

// ---------------------------------------------------------------------------
// Proj GEMM, 256x256 tile, 8-phase counted-vmcnt schedule (HK/m201 template),
// with the fused per-region epilogue:
//   z[0,2048): plain bf16 store
//   x[2048,4096): xsum (row-sum over head) then *gamma
//   B[4096,6144): rmsnorm(row)*Bn_w + B_bias ; C[6144,8192): same w/ Cn_w
__global__ __launch_bounds__(512, 2) void gemm_proj256(
    const bf16* __restrict__ A, const bf16* __restrict__ B, bf16* __restrict__ Cout,
    const float* __restrict__ gamma_buf, float* __restrict__ xsum,
    const float* __restrict__ Bn_w, const float* __restrict__ Cn_w,
    const float* __restrict__ B_bias, const float* __restrict__ C_bias)
{
  __shared__ bf16 lds[65536];          // 128 KiB: 8 half-slots x 8192 elems
  const int tid = threadIdx.x, wid = tid >> 6, lane = tid & 63;
  const int bid = blockIdx.x;
  const int swz = (bid & 7) * 128 + (bid >> 3);
  const int by = swz >> 5, bx = swz & 31;     // 32x32 tiles of 256
  const int m0 = by * 256, n0 = bx * 256;
  const int wr = wid >> 2, wc = wid & 3;      // wave -> (2M x 4N)
  const int fl = lane & 15, fq = lane >> 4;   // fragment lane coords
  const int rloc = wid * 8 + (lane >> 3);
  const int colSwz = ((lane & 7) ^ (lane >> 3)) * 8;

  fx4 acc[8][4];
  #pragma unroll
  for (int i = 0; i < 8; ++i)
    #pragma unroll
    for (int j = 0; j < 4; ++j) { fx4 z = {0.f, 0.f, 0.f, 0.f}; acc[i][j] = z; }

  const bf16* gA = A + (size_t)(m0 + rloc) * 1024 + colSwz;
  const bf16* gB = B + (size_t)(n0 + rloc) * 1024 + colSwz;

  // stage half h (0=B0,1=B1,2=A0,3=A1) of K-tile u; LDS slot = (4u+h) & 7.
  auto STAGE = [&](int u, int h) {
    const bf16* s = (h < 2) ? gB : gA;
    s += (size_t)(h & 1) * 128 * 1024 + u * 64;
    bf16* d = &lds[((u & 1) * 4 + h) * 8192 + wid * 512];   // wave-uniform
    async_copy16(d, s);
    async_copy16(d + 4096, s + 64 * 1024);
  };

  STAGE(0, 0); STAGE(0, 1); STAGE(0, 2); STAGE(0, 3);
  STAGE(1, 0); STAGE(1, 1);
  asm volatile("s_waitcnt vmcnt(4)" ::: "memory");
  __builtin_amdgcn_s_barrier();

  const int NT = 16;                    // K = 1024
  bf16x8 bfrag[4][2];
  for (int t = 0; t < NT; ++t) {
    const int Bb = (t & 1) * 32768;     // B-tile element base
    const int Ab = Bb + 16384;          // A-tile element base
    #pragma unroll
    for (int p = 0; p < 4; ++p) {
      bf16x8 af[2][2];
      if (p == 0) {
        #pragma unroll
        for (int j = 0; j < 4; ++j) {
          int nn = wc * 64 + j * 16 + fl;
          #pragma unroll
          for (int kk = 0; kk < 2; ++kk) {
            int q = (kk * 4 + fq) ^ (nn & 7);
            bfrag[j][kk] = *(const bf16x8*)&lds[Bb + nn * 64 + q * 8];
          }
        }
      }
      #pragma unroll
      for (int ii = 0; ii < 2; ++ii) {
        int mm = wr * 128 + (p * 2 + ii) * 16 + fl;
        #pragma unroll
        for (int kk = 0; kk < 2; ++kk) {
          int q = (kk * 4 + fq) ^ (mm & 7);
          af[ii][kk] = *(const bf16x8*)&lds[Ab + mm * 64 + q * 8];
        }
      }
      {
        int H = 4 * t + 6 + p;
        if (H < 4 * NT) STAGE(H >> 2, H & 3);
      }
      if (p == 3) asm volatile("s_waitcnt vmcnt(4)" ::: "memory");
      __builtin_amdgcn_s_barrier();
      asm volatile("s_waitcnt lgkmcnt(0)" ::: "memory");
      __builtin_amdgcn_sched_barrier(0);
      __builtin_amdgcn_s_setprio(1);
      #pragma unroll
      for (int ii = 0; ii < 2; ++ii)
        #pragma unroll
        for (int j = 0; j < 4; ++j)
          #pragma unroll
          for (int kk = 0; kk < 2; ++kk)
            acc[p * 2 + ii][j] = __builtin_amdgcn_mfma_f32_16x16x32_bf16(
                af[ii][kk], bfrag[j][kk], acc[p * 2 + ii][j], 0, 0, 0);
      __builtin_amdgcn_s_setprio(0);
      __builtin_amdgcn_s_barrier();
    }
  }

  // ---- fused epilogue ----
  const int reg = bx >> 3;                       // 0=z 1=x 2=B 3=C
  const int hh = ((n0 + wc * 64) & 2047) >> 6;   // head for this wave
  const int mwb = m0 + wr * 128;
  const int nwb = n0 + wc * 64;
  if (reg == 0) {
    #pragma unroll
    for (int i = 0; i < 8; ++i)
      #pragma unroll
      for (int j = 0; j < 4; ++j)
        #pragma unroll
        for (int r = 0; r < 4; ++r) {
          int m = mwb + i * 16 + fq * 4 + r;
          int n = nwb + j * 16 + fl;
          Cout[(size_t)m * 8192 + n] = (bf16)acc[i][j][r];
        }
  } else if (reg == 1) {
    #pragma unroll
    for (int i = 0; i < 8; ++i)
      #pragma unroll
      for (int r = 0; r < 4; ++r) {
        float s = acc[i][0][r] + acc[i][1][r] + acc[i][2][r] + acc[i][3][r];
        s = red16(s);
        int m = mwb + i * 16 + fq * 4 + r;
        if (fl == 0) xsum[(size_t)m * 32 + hh] = s;
        float g = gamma_buf[(size_t)m * 32 + hh];
        #pragma unroll
        for (int j = 0; j < 4; ++j) {
          int n = nwb + j * 16 + fl;
          Cout[(size_t)m * 8192 + n] = (bf16)(acc[i][j][r] * g);
        }
      }
  } else {
    const float* w = (reg == 2) ? Bn_w : Cn_w;
    const float* bias = (reg == 2) ? B_bias : C_bias;
    #pragma unroll
    for (int i = 0; i < 8; ++i)
      #pragma unroll
      for (int r = 0; r < 4; ++r) {
        float ss = acc[i][0][r] * acc[i][0][r] + acc[i][1][r] * acc[i][1][r]
                 + acc[i][2][r] * acc[i][2][r] + acc[i][3][r] * acc[i][3][r];
        ss = red16(ss);
        float sc = rsqrtf(ss * (1.f / 64.f) + 1e-5f);
        int m = mwb + i * 16 + fq * 4 + r;
        #pragma unroll
        for (int j = 0; j < 4; ++j) {
          int c = j * 16 + fl;
          Cout[(size_t)m * 8192 + nwb + c] =
              (bf16)(acc[i][j][r] * sc * w[c] + bias[hh * 64 + c]);
        }
      }
  }
}

// ---------------------------------------------------------------------------
// Generic 128x256-tile 8-phase GEMM, same counted-vmcnt schedule as
// gemm_proj256 (harness-verified); parameter variant: BM=128, BN=256, BK=64.
// LDS = 6-slot ring x 16KB = 96 KiB (3 halves per K-tile: B0,B1,A).
// Issue plan per K-tile t: p0 -> A(t+1), p1 -> B0(t+2), p2 -> B1(t+2),
// p3 -> vmcnt(4) (the 4 allowed in-flight = B0,B1 of t+2) => tile t+1 landed.
// WAR: A(t+1) overwrites A(t-1) [last read p3(t-1), >=1 barrier before issue];
//      B(t+2) overwrites B(t) [read only at p0(t), >=1 barrier before issue].
// C = A(MxK, lda) * B^T(NxK). MODE 1 = bf16 store, MODE 2 = f32 + resid.
// Requirements: M%128==0, N%256==0, K%64==0, grid%8==0.
template <int MODE>
__global__ __launch_bounds__(512, 2) void gemm128x256(
    const bf16* __restrict__ A, const bf16* __restrict__ B, void* __restrict__ Cout,
    const float* __restrict__ resid, int NT, int lda, int ldc, int nbx)
{
  __shared__ bf16 lds[49152];          // 96 KiB: 6 half-slots x 8192 elems
  const int tid = threadIdx.x, wid = tid >> 6, lane = tid & 63;
  const int cpx = gridDim.x >> 3;
  const int bid = blockIdx.x;
  const int swz = (bid & 7) * cpx + (bid >> 3);
  const int by = swz / nbx, bx = swz - by * nbx;
  const int m0 = by * 128, n0 = bx * 256;
  const int wr = wid >> 2, wc = wid & 3;       // wave -> (2M x 4N), 64x64 each
  const int fl = lane & 15, fq = lane >> 4;
  const int rloc = wid * 8 + (lane >> 3);      // 0..63
  const int colSwz = ((lane & 7) ^ (lane >> 3)) * 8;
  const int K = NT * 64;

  fx4 acc[4][4];
  #pragma unroll
  for (int i = 0; i < 4; ++i)
    #pragma unroll
    for (int j = 0; j < 4; ++j) { fx4 z = {0.f, 0.f, 0.f, 0.f}; acc[i][j] = z; }

  const bf16* gA = A + (size_t)(m0 + rloc) * lda + colSwz;
  const bf16* gB = B + (size_t)(n0 + rloc) * K + colSwz;

  // stage half h (0=B rows 0-127, 1=B rows 128-255, 2=A rows 0-127) of tile u.
  auto STAGE = [&](int u, int h) {
    const bf16* s;
    size_t str;
    if (h < 2) { s = gB + (size_t)h * 128 * K; str = (size_t)K; }
    else       { s = gA;                       str = (size_t)lda; }
    s += u * 64;
    bf16* d = &lds[((u & 1) * 3 + h) * 8192 + wid * 512];   // wave-uniform
    async_copy16(d, s);
    async_copy16(d + 4096, s + 64 * str);
  };

  // prologue: tile0 complete + B0,B1 of tile1 (A of tile1 issues at t=0,p0).
  STAGE(0, 0); STAGE(0, 1); STAGE(0, 2);
  STAGE(1, 0); STAGE(1, 1);
  asm volatile("s_waitcnt vmcnt(4)" ::: "memory");
  __builtin_amdgcn_s_barrier();

  bf16x8 bfrag[4][2];
  for (int t = 0; t < NT; ++t) {
    const int base = (t & 1) * 24576;
    #pragma unroll
    for (int p = 0; p < 4; ++p) {
      bf16x8 af[2];
      if (p == 0) {
        #pragma unroll
        for (int j = 0; j < 4; ++j) {
          int nn = wc * 64 + j * 16 + fl;                // 0..255
          #pragma unroll
          for (int kk = 0; kk < 2; ++kk) {
            int q = (kk * 4 + fq) ^ (nn & 7);
            bfrag[j][kk] = *(const bf16x8*)&lds[base + (nn >> 7) * 8192 + (nn & 127) * 64 + q * 8];
          }
        }
      }
      {
        int mm = wr * 64 + p * 16 + fl;                  // 0..127
        #pragma unroll
        for (int kk = 0; kk < 2; ++kk) {
          int q = (kk * 4 + fq) ^ (mm & 7);
          af[kk] = *(const bf16x8*)&lds[base + 2 * 8192 + mm * 64 + q * 8];
        }
      }
      if (p == 0)      { if (t + 1 < NT) STAGE(t + 1, 2); }
      else if (p == 1) { if (t + 2 < NT) STAGE(t + 2, 0); }
      else if (p == 2) { if (t + 2 < NT) STAGE(t + 2, 1); }
      if (p == 3) asm volatile("s_waitcnt vmcnt(4)" ::: "memory");
      __builtin_amdgcn_s_barrier();
      asm volatile("s_waitcnt lgkmcnt(0)" ::: "memory");
      __builtin_amdgcn_sched_barrier(0);
      __builtin_amdgcn_s_setprio(1);
      #pragma unroll
      for (int j = 0; j < 4; ++j)
        #pragma unroll
        for (int kk = 0; kk < 2; ++kk)
          acc[p][j] = __builtin_amdgcn_mfma_f32_16x16x32_bf16(
              af[kk], bfrag[j][kk], acc[p][j], 0, 0, 0);
      __builtin_amdgcn_s_setprio(0);
      __builtin_amdgcn_s_barrier();
    }
  }

  const int mwb = m0 + wr * 64;
  const int nwb = n0 + wc * 64;
  #pragma unroll
  for (int i = 0; i < 4; ++i)
    #pragma unroll
    for (int j = 0; j < 4; ++j)
      #pragma unroll
      for (int r = 0; r < 4; ++r) {
        int m = mwb + i * 16 + fq * 4 + r;
        int n = nwb + j * 16 + fl;
        size_t off = (size_t)m * ldc + n;
        float v = acc[i][j][r];
        if (MODE == 1) ((bf16*)Cout)[off] = (bf16)v;
        else ((float*)Cout)[off] = v + resid[off];
      }
}

// ---------------------------------------------------------------------------
// Chunk sums of dt*theta: S[(b*64+c)][h*32+d], head-quartered grid (128,4).
__global__ __launch_bounds__(256) void chunk_sum_kernel(
    const float* __restrict__ projT, float* __restrict__ S)
{
  __shared__ float lds[8 * 288];   // 8 rows x (32 dt + 256 theta)
  const int blk = blockIdx.x;      // b*64 + c
  const int hq = blockIdx.y;       // head quarter
  const size_t row0 = (size_t)blk * 64;
  const int tid = threadIdx.x;
  float s = 0.f;
  #pragma unroll 1
  for (int batch = 0; batch < 8; ++batch) {
    __syncthreads();
    const float* src = projT + (row0 + batch * 8) * 1152;
    #pragma unroll
    for (int i = 0; i < 9; ++i) {
      int idx = i * 256 + tid;
      int r = idx / 288, col = idx - r * 288;
      int gcol = (col < 32) ? col : (32 + hq * 256 + (col - 32));
      lds[idx] = src[r * 1152 + gcol];
    }
    __syncthreads();
    int hl = tid >> 5, d = tid & 31;
    #pragma unroll
    for (int r = 0; r < 8; ++r)
      s += lds[r * 288 + hq * 8 + hl] * lds[r * 288 + 32 + hl * 32 + d];
  }
  S[(size_t)blk * 1024 + hq * 256 + tid] = s;
}

// ---------------------------------------------------------------------------
// RoPE apply, one block per (b,c,h).
__global__ __launch_bounds__(256) void rope_kernel(
    bf16* proj, const float* __restrict__ projT, const float* __restrict__ S)
{
  __shared__ float angs[64 * 33], angc[64 * 33];
  const int blk = blockIdx.x;
  const int b = blk >> 11, c = (blk >> 5) & 63, h = blk & 31;
  const size_t t0 = (size_t)b * 4096 + c * 64;
  const int w = threadIdx.x >> 6, lane = threadIdx.x & 63;
  const float* tr = projT + (t0 + lane) * 1152;
  float dtv = tr[h];
  const float* thp = tr + 32 + h * 32 + w * 8;
  float4 th0 = *(const float4*)thp;
  float4 th1 = *(const float4*)(thp + 4);
  const float* Sp = S + (size_t)(b * 64 + lane) * 1024 + h * 32 + w * 8;
  float4 S0 = *(const float4*)Sp;
  float4 S1 = *(const float4*)(Sp + 4);
  float th[8] = { th0.x, th0.y, th0.z, th0.w, th1.x, th1.y, th1.z, th1.w };
  float Sv[8] = { S0.x, S0.y, S0.z, S0.w, S1.x, S1.y, S1.z, S1.w };
  #pragma unroll 1
  for (int j = 0; j < 8; ++j) {
    int d = w * 8 + j;
    float sv = (lane < c) ? Sv[j] : 0.f;
    float off = warp_sum64(sv);
    float v = dtv * th[j];
    #pragma unroll
    for (int o = 1; o < 64; o <<= 1) { float u = __shfl_up(v, o); if (lane >= o) v += u; }
    float ang = off + v;
    float sn, cs;
    sincosf(ang, &sn, &cs);
    angs[lane * 33 + d] = sn;
    angc[lane * 33 + d] = cs;
  }
  __syncthreads();
  const int tt = threadIdx.x >> 2, q = threadIdx.x & 3;
  const size_t base = (t0 + tt) * 8192 + 4096 + h * 64 + q * 16;
  #pragma unroll
  for (int m = 0; m < 2; ++m) {   // m=0: B, m=1: C
    bf16* p = proj + base + m * 2048;
    bf16x8 v0 = *(const bf16x8*)(p);
    bf16x8 v1 = *(const bf16x8*)(p + 8);
    bf16x8 r0, r1;
    #pragma unroll
    for (int pp = 0; pp < 4; ++pp) {
      int d = q * 8 + pp;
      float e1 = (float)v0[2 * pp], e2 = (float)v0[2 * pp + 1];
      float sn = angs[tt * 33 + d], cs = angc[tt * 33 + d];
      r0[2 * pp]     = (bf16)(cs * e1 - sn * e2);
      r0[2 * pp + 1] = (bf16)(sn * e1 + cs * e2);
    }
    #pragma unroll
    for (int pp = 0; pp < 4; ++pp) {
      int d = q * 8 + 4 + pp;
      float e1 = (float)v1[2 * pp], e2 = (float)v1[2 * pp + 1];
      float sn = angs[tt * 33 + d], cs = angc[tt * 33 + d];
      r1[2 * pp]     = (bf16)(cs * e1 - sn * e2);
      r1[2 * pp + 1] = (bf16)(sn * e1 + cs * e2);
    }
    *(bf16x8*)(p) = r0;
    *(bf16x8*)(p + 8) = r1;
  }
}

// ---------------------------------------------------------------------------
// SSD stage 1 (MFMA), one block per (b,c,h) with blk = b*2048+c*32+h.
__global__ __launch_bounds__(256) void ssd1_kernel(
    const bf16* __restrict__ proj, const float* __restrict__ a_buf,
    bf16* __restrict__ Bx, bf16* __restrict__ states,
    float* __restrict__ rowsum, float* __restrict__ expac, float* __restrict__ dchunk)
{
  __shared__ bf16 Xs[64 * 72], Bs[64 * 72];
  __shared__ float acum[64], dsv[64];
  const int blk = blockIdx.x;
  const int h = blk & 31;
  const size_t bs0 = ((size_t)(blk >> 5)) * 64;
  const int tid = threadIdx.x;
  const int l = tid >> 2, p0 = (tid & 3) * 16;
  {
    const bf16* xrow = proj + (bs0 + l) * 8192 + 2048 + h * 64 + p0;
    *(bf16x8*)&Xs[l * 72 + p0]     = ((const bf16x8*)xrow)[0];
    *(bf16x8*)&Xs[l * 72 + p0 + 8] = ((const bf16x8*)xrow)[1];
    const bf16* brow = proj + (bs0 + l) * 8192 + 4096 + h * 64 + p0;
    *(bf16x8*)&Bs[l * 72 + p0]     = ((const bf16x8*)brow)[0];
    *(bf16x8*)&Bs[l * 72 + p0 + 8] = ((const bf16x8*)brow)[1];
  }
  if (tid < 64) {
    float v = a_buf[(bs0 + tid) * 32 + h];
    #pragma unroll
    for (int o = 1; o < 64; o <<= 1) { float u = __shfl_up(v, o); if (tid >= o) v += u; }
    acum[tid] = v;
    float a63 = __shfl(v, 63);
    dsv[tid] = expf(a63 - v);
    expac[(size_t)blk * 64 + tid] = expf(v);
    if (tid == 63) dchunk[blk] = expf(v);
  }
  __syncthreads();
  {
    float al = acum[l];
    float rs = 0.f;
    for (int s = tid & 3; s <= l; s += 4) rs += expf(al - acum[s]);
    rs += __shfl_xor(rs, 1);
    rs += __shfl_xor(rs, 2);
    if ((tid & 3) == 0) rowsum[(size_t)blk * 64 + l] = rs + (float)(63 - l);
  }
  const int wv = tid >> 6, lane = tid & 63;
  const int mi = lane & 15, kq = lane >> 4;
  const int m0 = wv * 16;
  fx4 accB[4], accS[4];
  #pragma unroll
  for (int j4 = 0; j4 < 4; ++j4) { fx4 z = {0.f,0.f,0.f,0.f}; accB[j4] = z; accS[j4] = z; }
  #pragma unroll
  for (int kk = 0; kk < 2; ++kk) {
    const int lb = kk * 32 + kq * 8;
    bf16x8 aX, aXd;
    #pragma unroll
    for (int j = 0; j < 8; ++j) {
      bf16 xv = Xs[(lb + j) * 72 + m0 + mi];
      aX[j] = xv;
      aXd[j] = (bf16)((float)xv * dsv[lb + j]);
    }
    #pragma unroll
    for (int j4 = 0; j4 < 4; ++j4) {
      bf16x8 bB;
      #pragma unroll
      for (int j = 0; j < 8; ++j) bB[j] = Bs[(lb + j) * 72 + j4 * 16 + mi];
      accB[j4] = __builtin_amdgcn_mfma_f32_16x16x32_bf16(aX, bB, accB[j4], 0, 0, 0);
      accS[j4] = __builtin_amdgcn_mfma_f32_16x16x32_bf16(aXd, bB, accS[j4], 0, 0, 0);
    }
  }
  const size_t obase = (size_t)blk * 4096;
  #pragma unroll
  for (int j4 = 0; j4 < 4; ++j4) {
    #pragma unroll
    for (int r = 0; r < 4; ++r) {
      int p = m0 + kq * 4 + r;
      int n = j4 * 16 + mi;
      Bx[obase + p * 64 + n] = (bf16)accB[j4][r];
      states[obase + p * 64 + n] = (bf16)accS[j4][r];
    }
  }
}

// ---------------------------------------------------------------------------
// SSD stage 2: inclusive scan over chunks (f32 carry, bf16 storage).
__global__ __launch_bounds__(128) void ssd2_kernel(
    bf16* __restrict__ states, const float* __restrict__ dchunk)
{
  const int blk = blockIdx.x;  // 1024 = b(2) x h(32) x q(16)
  const int b = blk >> 9, rest = blk & 511;
  const int h = rest >> 4, q = rest & 15;
  const int e0 = q * 256 + threadIdx.x * 2;
  float fs0 = 0.f, fs1 = 0.f;
  #pragma unroll 2
  for (int c = 0; c < 64; ++c) {
    size_t idx = ((size_t)(b * 2048 + c * 32 + h) * 4096) + e0;
    float dec = dchunk[b * 2048 + c * 32 + h];
    bf16x2 st = *(const bf16x2*)(states + idx);
    fs0 = fs0 * dec + (float)st[0];
    fs1 = fs1 * dec + (float)st[1];
    bf16x2 o = { (bf16)fs0, (bf16)fs1 };
    *(bf16x2*)(states + idx) = o;
  }
}

// ---------------------------------------------------------------------------
// SSD stage 3 (MFMA), one block per (b,c,h).
__global__ __launch_bounds__(256) void ssd3_kernel(
    bf16* proj, const bf16* __restrict__ Bx, const bf16* __restrict__ FS,
    const float* __restrict__ rowsum, const float* __restrict__ expac,
    const float* __restrict__ xsum, const float* __restrict__ D_param)
{
  __shared__ bf16 Cs[64 * 72], BxS[64 * 72], FSs[64 * 72];
  __shared__ float rs_s[64], ea_s[64], sk_s[64];
  const int blk = blockIdx.x;
  const int h = blk & 31;
  const size_t bs0 = ((size_t)(blk >> 5)) * 64;
  const int tid = threadIdx.x;
  const int l = tid >> 2, q0 = (tid & 3) * 16;
  {
    const bf16* crow = proj + (bs0 + l) * 8192 + 6144 + h * 64 + q0;
    *(bf16x8*)&Cs[l * 72 + q0]     = ((const bf16x8*)crow)[0];
    *(bf16x8*)&Cs[l * 72 + q0 + 8] = ((const bf16x8*)crow)[1];
    size_t mb = (size_t)blk * 4096 + l * 64 + q0;
    *(bf16x8*)&BxS[l * 72 + q0]     = ((const bf16x8*)(Bx + mb))[0];
    *(bf16x8*)&BxS[l * 72 + q0 + 8] = ((const bf16x8*)(Bx + mb))[1];
    *(bf16x8*)&FSs[l * 72 + q0]     = ((const bf16x8*)(FS + mb))[0];
    *(bf16x8*)&FSs[l * 72 + q0 + 8] = ((const bf16x8*)(FS + mb))[1];
  }
  if (tid < 64) {
    rs_s[tid] = rowsum[(size_t)blk * 64 + tid];
    ea_s[tid] = expac[(size_t)blk * 64 + tid];
    sk_s[tid] = D_param[h] * xsum[(bs0 + tid) * 32 + h];
  }
  __syncthreads();
  const int wv = tid >> 6, lane = tid & 63;
  const int mi = lane & 15, kq = lane >> 4;
  const int m0 = wv * 16;
  fx4 acc1[4], acc2[4];
  #pragma unroll
  for (int j4 = 0; j4 < 4; ++j4) { fx4 z = {0.f,0.f,0.f,0.f}; acc1[j4] = z; acc2[j4] = z; }
  #pragma unroll
  for (int kk = 0; kk < 2; ++kk) {
    bf16x8 aC = *(const bf16x8*)&Cs[(m0 + mi) * 72 + kk * 32 + kq * 8];
    #pragma unroll
    for (int j4 = 0; j4 < 4; ++j4) {
      bf16x8 bx = *(const bf16x8*)&BxS[(j4 * 16 + mi) * 72 + kk * 32 + kq * 8];
      bf16x8 fs = *(const bf16x8*)&FSs[(j4 * 16 + mi) * 72 + kk * 32 + kq * 8];
      acc1[j4] = __builtin_amdgcn_mfma_f32_16x16x32_bf16(aC, bx, acc1[j4], 0, 0, 0);
      acc2[j4] = __builtin_amdgcn_mfma_f32_16x16x32_bf16(aC, fs, acc2[j4], 0, 0, 0);
    }
  }
  #pragma unroll
  for (int j4 = 0; j4 < 4; ++j4) {
    #pragma unroll
    for (int r = 0; r < 4; ++r) {
      int li = m0 + kq * 4 + r;
      int p = j4 * 16 + mi;
      float y = rs_s[li] * acc1[j4][r] + ea_s[li] * acc2[j4][r] + sk_s[li];
      size_t zoff = (bs0 + li) * 8192 + h * 64 + p;
      float z = (float)proj[zoff];
      proj[zoff + 2048] = (bf16)(y * z * sigmoid_f(z));
    }
  }
}

// ---------------------------------------------------------------------------
__global__ __launch_bounds__(256) void silu_mul_kernel(
    const bf16* __restrict__ gu, bf16* __restrict__ m)
{
  const size_t row = blockIdx.y;
  const int col2 = blockIdx.x * 256 + threadIdx.x;  // 0..1279
  const size_t gi = row * 5120 + col2 * 2;
  bf16x2 g = *(const bf16x2*)(gu + gi);
  bf16x2 u = *(const bf16x2*)(gu + gi + 2560);
  float g0 = (float)g[0], g1 = (float)g[1];
  float m0 = g0 * sigmoid_f(g0) * (float)u[0];
  float m1 = g1 * sigmoid_f(g1) * (float)u[1];
  bf16x2 mv = { (bf16)m0, (bf16)m1 };
  *(bf16x2*)(m + row * 2560 + col2 * 2) = mv;
}

// ---------------------------------------------------------------------------
extern "C" void kernel_launch(void* const* d_in, const int* in_sizes, int n_in,
                              void* d_out, int out_size, void* d_ws, size_t ws_size,
                              hipStream_t stream) {
  (void)in_sizes; (void)n_in; (void)out_size;
  if (ws_size < WS_NEEDED) return;  // diagnostic guard: fail absmax, not SIGABRT
  const float* x       = (const float*)d_in[0];
  const float* n1w     = (const float*)d_in[1];
  const float* n2w     = (const float*)d_in[2];
  const float* W_in    = (const float*)d_in[3];
  const float* W_out   = (const float*)d_in[4];
  const float* A_log   = (const float*)d_in[5];
  const float* D_param = (const float*)d_in[6];
  const float* dt_bias = (const float*)d_in[7];
  const float* B_bias  = (const float*)d_in[8];
  const float* C_bias  = (const float*)d_in[9];
  const float* Bn_w    = (const float*)d_in[10];
  const float* Cn_w    = (const float*)d_in[11];
  const float* Wg      = (const float*)d_in[12];
  const float* Wu      = (const float*)d_in[13];
  const float* Wd      = (const float*)d_in[14];
  float* out = (float*)d_out;
  char* ws = (char*)d_ws;

  bf16*  proj   = (bf16*)(ws + OFF_PROJ);
  float* projT  = (float*)(ws + OFF_PROJT);
  bf16*  h_hi   = (bf16*)(ws + OFF_HHI);
  bf16*  h_lo   = (bf16*)(ws + OFF_HLO);
  bf16*  Wt_in  = (bf16*)(ws + OFF_WTIN);
  bf16*  Wt_hi  = (bf16*)(ws + OFF_WTHI);
  bf16*  Wt_lo  = (bf16*)(ws + OFF_WTLO);
  bf16*  Wt_out = (bf16*)(ws + OFF_WTOUT);
  bf16*  Wt_gu  = (bf16*)(ws + OFF_WTGU);
  bf16*  Wt_d   = (bf16*)(ws + OFF_WTD);
  bf16*  Bx     = (bf16*)(ws + OFF_BX);
  bf16*  states = (bf16*)(ws + OFF_STATES);
  float* a_buf  = (float*)(ws + OFF_ABUF);
  float* xsum_  = (float*)(ws + OFF_XSUM);
  float* rowsum = (float*)(ws + OFF_ROWSUM);
  float* expac  = (float*)(ws + OFF_EXPA);
  float* dchunk = (float*)(ws + OFF_DCHUNK);
  float* gamma_ = (float*)(ws + OFF_GAMMA);
  float* Ssum   = (float*)(ws + OFF_HLO);    // 512KB chunk sums (h_lo dead by then)
  bf16*  ybf    = proj + 2048;               // cols [2048,4096) of proj, lda 8192
  bf16*  gubf   = (bf16*)(ws + OFF_GU);
  bf16*  mbf    = (bf16*)(ws + OFF_MBF);
  bf16*  h2bf   = h_hi;                      // reuse after proj GEMMs
  float* x2     = out;                       // x2 lives in d_out

  // --- weight transposes needed up-front ---
  transpose_cast<<<dim3(256, 32), 256, 0, stream>>>(W_in, 9248, 0, Wt_in, 1024, 8192);
  transpose_cast_hilo<<<dim3(36, 32), 256, 0, stream>>>(W_in, 9248, 8192, Wt_hi, Wt_lo, 1024, 1056);

  // --- norm1 (hi/lo split for the precision-critical dt/theta tail GEMM) ---
  rmsnorm_kernel<<<8192, 256, 0, stream>>>(x, n1w, h_hi, h_lo);

  // --- in-projection: fused hi/lo tail, then dt, then proj w/ fused prep ---
  gemm_tail<<<dim3(9, 64), 256, 0, stream>>>(h_hi, h_lo, Wt_hi, Wt_lo, projT);
  dt_kernel<<<1024, 256, 0, stream>>>(projT, A_log, dt_bias, a_buf, gamma_);
  gemm_proj256<<<dim3(1024), 512, 0, stream>>>(h_hi, Wt_in, proj, gamma_, xsum_,
                                               Bn_w, Cn_w, B_bias, C_bias);

  // --- hierarchical RoPE ---
  chunk_sum_kernel<<<dim3(128, 4), 256, 0, stream>>>(projT, Ssum);
  rope_kernel<<<4096, 256, 0, stream>>>(proj, projT, Ssum);

  // --- SSD (MFMA) ---
  ssd1_kernel<<<4096, 256, 0, stream>>>(proj, a_buf, Bx, states, rowsum, expac, dchunk);
  ssd2_kernel<<<1024, 128, 0, stream>>>(states, dchunk);
  ssd3_kernel<<<4096, 256, 0, stream>>>(proj, Bx, states, rowsum, expac, xsum_, D_param);

  // --- late weight transposes (overlay dead states region) ---
  transpose_cast<<<dim3(32, 64), 256, 0, stream>>>(W_out, 1024, 0, Wt_out, 2048, 1024);
  transpose_cast<<<dim3(80, 32), 256, 0, stream>>>(Wg, 2560, 0, Wt_gu, 1024, 2560);
  transpose_cast<<<dim3(80, 32), 256, 0, stream>>>(Wu, 2560, 0, Wt_gu + (size_t)2560 * 1024, 1024, 2560);
  transpose_cast<<<dim3(32, 80), 256, 0, stream>>>(Wd, 1024, 0, Wt_d, 2560, 1024);

  // --- out-projection + residual (x2 -> d_out) ---
  // M=8192, N=1024, K=2048 -> grid 64x4 = 256 blocks = exactly 1 round.
  gemm128x256<2><<<dim3(256), 512, 0, stream>>>(ybf, Wt_out, x2, x, 32, 8192, 1024, 4);

  // --- MLP ---
  rmsnorm_kernel<<<8192, 256, 0, stream>>>(x2, n2w, h2bf, nullptr);
  // gu: M=8192, N=5120, K=1024 -> grid 64x20 = 1280 blocks = exactly 5 rounds.
  gemm128x256<1><<<dim3(1280), 512, 0, stream>>>(h2bf, Wt_gu, gubf, nullptr, 16, 1024, 5120, 20);
  silu_mul_kernel<<<dim3(5, 8192), 256, 0, stream>>>(gubf, mbf);
  // down: M=8192, N=1024, K=2560 -> grid 64x4 = 256 blocks = exactly 1 round.
  gemm128x256<2><<<dim3(256), 512, 0, stream>>>(mbf, Wt_d, out, x2, 40, 2560, 1024, 4);
}

// Round 5
// 741.769 us; speedup vs baseline: 1.1213x; 1.0555x over previous
//
#include <hip/hip_runtime.h>
#include <cstdint>
#include <cmath>

// ---------------------------------------------------------------------------
// Mamba3 block forward, MI355X (gfx950).
// B=2, S=4096 (8192 tokens), D_MODEL=1024, D_INNER=2048, NHEADS=32, HD=64,
// D_STATE=64, CHUNK=64, D_MLP=2560, PROJ=9248.
// Workspace budget: ~251.5 MiB. x2 lives in d_out.
//
// R1: gemm_proj -> 256^2 8-phase counted-vmcnt schedule: 207 -> 162 us.
// R2: gu on 256^2 tiles REGRESSED (grid quantization: 640 blk = 2.5 rounds).
// R3: BM=128xBN=256 8-phase variant, exact-round grids for gu/out/down:
//     total 832 -> 783. (proj 160->188 cross-run clock variance, not code.)
// R4: (a) gu GEMM + silu fused (gemm_gusilu): block computes matching
//     g-tile AND u-tile (ws-split waves), u exchanged via LDS f32 in the
//     epilogue, mbf written directly -> gubf round-trip (168 MB) removed.
//     (b) drain fix in all 8-phase kernels: vmcnt(0) at t==NT-2.
// R5: resubmit of R4 unchanged — R4 bench was an infra failure (container
//     failed twice, no kernel signal); code re-audited for hang paths: none.
// ---------------------------------------------------------------------------

typedef __bf16 bf16;
typedef __bf16 bf16x2 __attribute__((ext_vector_type(2)));
typedef __bf16 bf16x4 __attribute__((ext_vector_type(4)));
typedef __bf16 bf16x8 __attribute__((ext_vector_type(8)));
typedef float fx4 __attribute__((ext_vector_type(4)));

#define DEV __device__ __forceinline__

// ---- workspace layout (bytes) ---------------------------------------------
#define OFF_PROJ    0ull
#define OFF_HHI     134217728ull   // 8192x1024 bf16 (h hi) ; later h2_bf
#define OFF_HLO     150994944ull   // 8192x1024 bf16 (h lo) ; later S (chunk sums, 512KB)
#define OFF_WTIN    167772160ull   // 8192x1024 bf16
#define OFF_WTHI    184549376ull   // 1152x1024 bf16
#define OFF_WTLO    186908672ull   // 1152x1024 bf16
#define OFF_PROJT   189267968ull   // 8192x1152 f32 (dt,theta) -- dead after rope
#define OFF_BX      189267968ull   // 4096x4096 bf16 (written at ssd1, overlays projT)
#define OFF_STATES  222822400ull   // 4096x4096 bf16 -> FS in place; dead after ssd3
#define OFF_WTOUT   222822400ull   // 1024x2048 bf16 (after ssd3, overlays states)
#define OFF_WTGU    227016704ull   // 5120x1024 bf16 (after ssd3)
#define OFF_WTD     237502464ull   // 1024x2560 bf16 (after ssd3)
#define OFF_ABUF    256376832ull   // 8192x32 f32 (per-token A)
#define OFF_XSUM    257425408ull   // 8192x32 f32
#define OFF_ROWSUM  258473984ull   // (2,64,32,64) f32
#define OFF_EXPA    260571136ull   // (2,64,32,64) f32
#define OFF_DCHUNK  262668288ull   // (2,64,32) f32
#define OFF_GAMMA   262684672ull   // 8192x32 f32
#define WS_NEEDED   263733248ull

#define OFF_MBF     83886080ull

// ---------------------------------------------------------------------------
DEV void async_copy16(void* lds, const void* gptr) {
  __builtin_amdgcn_global_load_lds(
      (const __attribute__((address_space(1))) unsigned int*)(gptr),
      (__attribute__((address_space(3))) unsigned int*)(lds),
      16, 0, 0);
}

DEV float warp_sum64(float v) {
  #pragma unroll
  for (int o = 32; o; o >>= 1) v += __shfl_xor(v, o);
  return v;
}

DEV float red16(float v) {   // reduce across 16-lane groups (cc dimension)
  v += __shfl_xor(v, 1); v += __shfl_xor(v, 2);
  v += __shfl_xor(v, 4); v += __shfl_xor(v, 8);
  return v;
}

DEV float softplus_f(float x) { return x > 20.f ? x : log1pf(expf(x)); }
DEV float sigmoid_f(float x) { return 1.f / (1.f + expf(-x)); }

// ---------------------------------------------------------------------------
__global__ __launch_bounds__(256) void transpose_cast(
    const float* __restrict__ src, int ld, int col0,
    bf16* __restrict__ dst, int R, int C)
{
  __shared__ float tile[32][33];
  const int c0 = blockIdx.x * 32, r0 = blockIdx.y * 32;
  const int tx = threadIdx.x & 31, ty = threadIdx.x >> 5;
  #pragma unroll
  for (int ii = 0; ii < 4; ++ii) {
    int i = ty + ii * 8;
    int c = c0 + tx;
    tile[i][tx] = (c < C) ? src[(size_t)(r0 + i) * ld + col0 + c] : 0.f;
  }
  __syncthreads();
  #pragma unroll
  for (int ii = 0; ii < 4; ++ii) {
    int i = ty + ii * 8;
    dst[(size_t)(c0 + i) * R + r0 + tx] = (bf16)tile[tx][i];
  }
}

__global__ __launch_bounds__(256) void transpose_cast_hilo(
    const float* __restrict__ src, int ld, int col0,
    bf16* __restrict__ dhi, bf16* __restrict__ dlo, int R, int C)
{
  __shared__ float tile[32][33];
  const int c0 = blockIdx.x * 32, r0 = blockIdx.y * 32;
  const int tx = threadIdx.x & 31, ty = threadIdx.x >> 5;
  #pragma unroll
  for (int ii = 0; ii < 4; ++ii) {
    int i = ty + ii * 8;
    int c = c0 + tx;
    tile[i][tx] = (c < C) ? src[(size_t)(r0 + i) * ld + col0 + c] : 0.f;
  }
  __syncthreads();
  #pragma unroll
  for (int ii = 0; ii < 4; ++ii) {
    int i = ty + ii * 8;
    float v = tile[tx][i];
    bf16 hi = (bf16)v;
    size_t o = (size_t)(c0 + i) * R + r0 + tx;
    dhi[o] = hi;
    dlo[o] = (bf16)(v - (float)hi);
  }
}

// ---------------------------------------------------------------------------
__global__ __launch_bounds__(256) void rmsnorm_kernel(
    const float* __restrict__ x, const float* __restrict__ w,
    bf16* __restrict__ hi, bf16* __restrict__ lo)
{
  __shared__ float red[4];
  const size_t row = blockIdx.x;
  const int tid = threadIdx.x;
  float4 v = ((const float4*)(x + row * 1024))[tid];
  float ss = v.x * v.x + v.y * v.y + v.z * v.z + v.w * v.w;
  ss = warp_sum64(ss);
  if ((tid & 63) == 0) red[tid >> 6] = ss;
  __syncthreads();
  float tot = red[0] + red[1] + red[2] + red[3];
  float s = rsqrtf(tot * (1.f / 1024.f) + 1e-5f);
  float4 wv = ((const float4*)w)[tid];
  float h0 = v.x * s * wv.x, h1 = v.y * s * wv.y, h2 = v.z * s * wv.z, h3 = v.w * s * wv.w;
  bf16x4 hv = { (bf16)h0, (bf16)h1, (bf16)h2, (bf16)h3 };
  *(bf16x4*)(hi + row * 1024 + tid * 4) = hv;
  if (lo) {
    bf16x4 lv = { (bf16)(h0 - (float)hv[0]), (bf16)(h1 - (float)hv[1]),
                  (bf16)(h2 - (float)hv[2]), (bf16)(h3 - (float)hv[3]) };
    *(bf16x4*)(lo + row * 1024 + tid * 4) = lv;
  }
}

// ---------------------------------------------------------------------------
// Fused hi/lo tail GEMM: out = Ahi*Whi^T + Ahi*Wlo^T + Alo*Whi^T (f32 out).
// M=8192, N=1152, K=1024, ldc=1152. 64KB LDS (4 tiles).
__global__ __launch_bounds__(256) void gemm_tail(
    const bf16* Ahi, const bf16* Alo, const bf16* Whi, const bf16* Wlo,
    float* Cout)
{
  __shared__ bf16 Ah[128 * 64], Al[128 * 64], Bh[128 * 64], Bl[128 * 64];
  const int tid = threadIdx.x, wid = tid >> 6, lane = tid & 63;
  const int m0 = blockIdx.y * 128, n0 = blockIdx.x * 128;
  const int wm = (wid & 1) * 64, wn = (wid >> 1) * 64;
  fx4 acc[4][4];
  #pragma unroll
  for (int i = 0; i < 4; ++i)
    #pragma unroll
    for (int j = 0; j < 4; ++j) { fx4 z = {0.f, 0.f, 0.f, 0.f}; acc[i][j] = z; }

  const int srow = wid * 32 + (lane >> 3);
  const int slot = lane & 7;

  for (int k0 = 0; k0 < 1024; k0 += 64) {
    __syncthreads();
    #pragma unroll
    for (int i = 0; i < 4; ++i) {
      int m = srow + i * 8;
      int cA = ((slot ^ (m & 7)) * 8);
      size_t ao = (size_t)(m0 + m) * 1024 + k0 + cA;
      async_copy16(&Ah[wid * 2048 + i * 512], Ahi + ao);
      async_copy16(&Al[wid * 2048 + i * 512], Alo + ao);
      int n = srow + i * 8;
      int cB = ((slot ^ (n & 7)) * 8);
      size_t bo = (size_t)(n0 + n) * 1024 + k0 + cB;
      async_copy16(&Bh[wid * 2048 + i * 512], Whi + bo);
      async_copy16(&Bl[wid * 2048 + i * 512], Wlo + bo);
    }
    __syncthreads();
    #pragma unroll
    for (int kk = 0; kk < 2; ++kk) {
      bf16x8 ah[4], al[4], bh[4], bl[4];
      #pragma unroll
      for (int i = 0; i < 4; ++i) {
        int mm = wm + i * 16 + (lane & 15);
        int sA = (kk * 4 + (lane >> 4)) ^ (mm & 7);
        ah[i] = *(const bf16x8*)&Ah[mm * 64 + sA * 8];
        al[i] = *(const bf16x8*)&Al[mm * 64 + sA * 8];
        int nn = wn + i * 16 + (lane & 15);
        int sB = (kk * 4 + (lane >> 4)) ^ (nn & 7);
        bh[i] = *(const bf16x8*)&Bh[nn * 64 + sB * 8];
        bl[i] = *(const bf16x8*)&Bl[nn * 64 + sB * 8];
      }
      #pragma unroll
      for (int i = 0; i < 4; ++i)
        #pragma unroll
        for (int j = 0; j < 4; ++j) {
          acc[i][j] = __builtin_amdgcn_mfma_f32_16x16x32_bf16(ah[i], bh[j], acc[i][j], 0, 0, 0);
          acc[i][j] = __builtin_amdgcn_mfma_f32_16x16x32_bf16(ah[i], bl[j], acc[i][j], 0, 0, 0);
          acc[i][j] = __builtin_amdgcn_mfma_f32_16x16x32_bf16(al[i], bh[j], acc[i][j], 0, 0, 0);
        }
    }
  }
  const int r0 = (lane >> 4) * 4, cc = lane & 15;
  #pragma unroll
  for (int i = 0; i < 4; ++i)
    #pragma unroll
    for (int j = 0; j < 4; ++j)
      #pragma unroll
      for (int r = 0; r < 4; ++r) {
        int m = m0 + wm + i * 16 + r0 + r;
        int n = n0 + wn + j * 16 + cc;
        Cout[(size_t)m * 1152 + n] = acc[i][j][r];
      }
}

// ---------------------------------------------------------------------------
// dt/a/gamma per (token, head); dt written back into projT col h.
__global__ __launch_bounds__(256) void dt_kernel(
    float* projT, const float* __restrict__ A_log, const float* __restrict__ dt_bias,
    float* __restrict__ a_buf, float* __restrict__ gamma_buf)
{
  const int idx = blockIdx.x * 256 + threadIdx.x;   // 0..262143
  const int t = idx >> 5, h = idx & 31;
  float dtr = projT[(size_t)t * 1152 + h] + dt_bias[h];
  float dt = softplus_f(dtr);
  float a = -expf(A_log[h]) * dt;
  float alpha = expf(a);
  float gamma = (alpha - 1.f) / (a + 1e-6f) * 0.5f + 1.f;
  projT[(size_t)t * 1152 + h] = dt;
  a_buf[idx] = a;
  gamma_buf[idx] = gamma;
}

// ---------------------------------------------------------------------------
// Proj GEMM, 256x256 tile, 8-phase counted-vmcnt schedule (HK/m201 template),
// with the fused per-region epilogue:
//   z[0,2048): plain bf16 store
//   x[2048,4096): xsum (row-sum over head) then *gamma
//   B[4096,6144): rmsnorm(row)*Bn_w + B_bias ; C[6144,8192): same w/ Cn_w
__global__ __launch_bounds__(512, 2) void gemm_proj256(
    const bf16* __restrict__ A, const bf16* __restrict__ B, bf16* __restrict__ Cout,
    const float* __restrict__ gamma_buf, float* __restrict__ xsum,
    const float* __restrict__ Bn_w, const float* __restrict__ Cn_w,
    const float* __restrict__ B_bias, const float* __restrict__ C_bias)
{
  __shared__ bf16 lds[65536];          // 128 KiB: 8 half-slots x 8192 elems
  const int tid = threadIdx.x, wid = tid >> 6, lane = tid & 63;
  const int bid = blockIdx.x;
  const int swz = (bid & 7) * 128 + (bid >> 3);
  const int by = swz >> 5, bx = swz & 31;     // 32x32 tiles of 256
  const int m0 = by * 256, n0 = bx * 256;
  const int wr = wid >> 2, wc = wid & 3;      // wave -> (2M x 4N)
  const int fl = lane & 15, fq = lane >> 4;   // fragment lane coords
  const int rloc = wid * 8 + (lane >> 3);
  const int colSwz = ((lane & 7) ^ (lane >> 3)) * 8;

  fx4 acc[8][4];
  #pragma unroll
  for (int i = 0; i < 8; ++i)
    #pragma unroll
    for (int j = 0; j < 4; ++j) { fx4 z = {0.f, 0.f, 0.f, 0.f}; acc[i][j] = z; }

  const bf16* gA = A + (size_t)(m0 + rloc) * 1024 + colSwz;
  const bf16* gB = B + (size_t)(n0 + rloc) * 1024 + colSwz;

  // stage half h (0=B0,1=B1,2=A0,3=A1) of K-tile u; LDS slot = (4u+h) & 7.
  auto STAGE = [&](int u, int h) {
    const bf16* s = (h < 2) ? gB : gA;
    s += (size_t)(h & 1) * 128 * 1024 + u * 64;
    bf16* d = &lds[((u & 1) * 4 + h) * 8192 + wid * 512];   // wave-uniform
    async_copy16(d, s);
    async_copy16(d + 4096, s + 64 * 1024);
  };

  STAGE(0, 0); STAGE(0, 1); STAGE(0, 2); STAGE(0, 3);
  STAGE(1, 0); STAGE(1, 1);
  asm volatile("s_waitcnt vmcnt(4)" ::: "memory");
  __builtin_amdgcn_s_barrier();

  const int NT = 16;                    // K = 1024
  bf16x8 bfrag[4][2];
  for (int t = 0; t < NT; ++t) {
    const int Bb = (t & 1) * 32768;     // B-tile element base
    const int Ab = Bb + 16384;          // A-tile element base
    #pragma unroll
    for (int p = 0; p < 4; ++p) {
      bf16x8 af[2][2];
      if (p == 0) {
        #pragma unroll
        for (int j = 0; j < 4; ++j) {
          int nn = wc * 64 + j * 16 + fl;
          #pragma unroll
          for (int kk = 0; kk < 2; ++kk) {
            int q = (kk * 4 + fq) ^ (nn & 7);
            bfrag[j][kk] = *(const bf16x8*)&lds[Bb + nn * 64 + q * 8];
          }
        }
      }
      #pragma unroll
      for (int ii = 0; ii < 2; ++ii) {
        int mm = wr * 128 + (p * 2 + ii) * 16 + fl;
        #pragma unroll
        for (int kk = 0; kk < 2; ++kk) {
          int q = (kk * 4 + fq) ^ (mm & 7);
          af[ii][kk] = *(const bf16x8*)&lds[Ab + mm * 64 + q * 8];
        }
      }
      {
        int H = 4 * t + 6 + p;
        if (H < 4 * NT) STAGE(H >> 2, H & 3);
      }
      // counted vmcnt once per K-tile; full drain at t==NT-2 so the final
      // tile's A-halves are guaranteed resident before t==NT-1 reads them.
      if (p == 3) {
        if (t == NT - 2) asm volatile("s_waitcnt vmcnt(0)" ::: "memory");
        else             asm volatile("s_waitcnt vmcnt(4)" ::: "memory");
      }
      __builtin_amdgcn_s_barrier();
      asm volatile("s_waitcnt lgkmcnt(0)" ::: "memory");
      __builtin_amdgcn_sched_barrier(0);
      __builtin_amdgcn_s_setprio(1);
      #pragma unroll
      for (int ii = 0; ii < 2; ++ii)
        #pragma unroll
        for (int j = 0; j < 4; ++j)
          #pragma unroll
          for (int kk = 0; kk < 2; ++kk)
            acc[p * 2 + ii][j] = __builtin_amdgcn_mfma_f32_16x16x32_bf16(
                af[ii][kk], bfrag[j][kk], acc[p * 2 + ii][j], 0, 0, 0);
      __builtin_amdgcn_s_setprio(0);
      __builtin_amdgcn_s_barrier();
    }
  }

  // ---- fused epilogue ----
  const int reg = bx >> 3;                       // 0=z 1=x 2=B 3=C
  const int hh = ((n0 + wc * 64) & 2047) >> 6;   // head for this wave
  const int mwb = m0 + wr * 128;
  const int nwb = n0 + wc * 64;
  if (reg == 0) {
    #pragma unroll
    for (int i = 0; i < 8; ++i)
      #pragma unroll
      for (int j = 0; j < 4; ++j)
        #pragma unroll
        for (int r = 0; r < 4; ++r) {
          int m = mwb + i * 16 + fq * 4 + r;
          int n = nwb + j * 16 + fl;
          Cout[(size_t)m * 8192 + n] = (bf16)acc[i][j][r];
        }
  } else if (reg == 1) {
    #pragma unroll
    for (int i = 0; i < 8; ++i)
      #pragma unroll
      for (int r = 0; r < 4; ++r) {
        float s = acc[i][0][r] + acc[i][1][r] + acc[i][2][r] + acc[i][3][r];
        s = red16(s);
        int m = mwb + i * 16 + fq * 4 + r;
        if (fl == 0) xsum[(size_t)m * 32 + hh] = s;
        float g = gamma_buf[(size_t)m * 32 + hh];
        #pragma unroll
        for (int j = 0; j < 4; ++j) {
          int n = nwb + j * 16 + fl;
          Cout[(size_t)m * 8192 + n] = (bf16)(acc[i][j][r] * g);
        }
      }
  } else {
    const float* w = (reg == 2) ? Bn_w : Cn_w;
    const float* bias = (reg == 2) ? B_bias : C_bias;
    #pragma unroll
    for (int i = 0; i < 8; ++i)
      #pragma unroll
      for (int r = 0; r < 4; ++r) {
        float ss = acc[i][0][r] * acc[i][0][r] + acc[i][1][r] * acc[i][1][r]
                 + acc[i][2][r] * acc[i][2][r] + acc[i][3][r] * acc[i][3][r];
        ss = red16(ss);
        float sc = rsqrtf(ss * (1.f / 64.f) + 1e-5f);
        int m = mwb + i * 16 + fq * 4 + r;
        #pragma unroll
        for (int j = 0; j < 4; ++j) {
          int c = j * 16 + fl;
          Cout[(size_t)m * 8192 + nwb + c] =
              (bf16)(acc[i][j][r] * sc * w[c] + bias[hh * 64 + c]);
        }
      }
  }
}

// ---------------------------------------------------------------------------
// Generic 128x256-tile 8-phase GEMM, same counted-vmcnt schedule as
// gemm_proj256 (harness-verified); parameter variant: BM=128, BN=256, BK=64.
// LDS = 6-slot ring x 16KB = 96 KiB (3 halves per K-tile: B0,B1,A).
// Issue plan per K-tile t: p0 -> A(t+1), p1 -> B0(t+2), p2 -> B1(t+2),
// p3 -> vmcnt(4) => tile t+1 landed; vmcnt(0) at t==NT-2 (drain fix).
// C = A(MxK, lda) * B^T(NxK). MODE 1 = bf16 store, MODE 2 = f32 + resid.
// Requirements: M%128==0, N%256==0, K%64==0, grid%8==0.
template <int MODE>
__global__ __launch_bounds__(512, 2) void gemm128x256(
    const bf16* __restrict__ A, const bf16* __restrict__ B, void* __restrict__ Cout,
    const float* __restrict__ resid, int NT, int lda, int ldc, int nbx)
{
  __shared__ bf16 lds[49152];          // 96 KiB: 6 half-slots x 8192 elems
  const int tid = threadIdx.x, wid = tid >> 6, lane = tid & 63;
  const int cpx = gridDim.x >> 3;
  const int bid = blockIdx.x;
  const int swz = (bid & 7) * cpx + (bid >> 3);
  const int by = swz / nbx, bx = swz - by * nbx;
  const int m0 = by * 128, n0 = bx * 256;
  const int wr = wid >> 2, wc = wid & 3;       // wave -> (2M x 4N), 64x64 each
  const int fl = lane & 15, fq = lane >> 4;
  const int rloc = wid * 8 + (lane >> 3);      // 0..63
  const int colSwz = ((lane & 7) ^ (lane >> 3)) * 8;
  const int K = NT * 64;

  fx4 acc[4][4];
  #pragma unroll
  for (int i = 0; i < 4; ++i)
    #pragma unroll
    for (int j = 0; j < 4; ++j) { fx4 z = {0.f, 0.f, 0.f, 0.f}; acc[i][j] = z; }

  const bf16* gA = A + (size_t)(m0 + rloc) * lda + colSwz;
  const bf16* gB = B + (size_t)(n0 + rloc) * K + colSwz;

  // stage half h (0=B rows 0-127, 1=B rows 128-255, 2=A rows 0-127) of tile u.
  auto STAGE = [&](int u, int h) {
    const bf16* s;
    size_t str;
    if (h < 2) { s = gB + (size_t)h * 128 * K; str = (size_t)K; }
    else       { s = gA;                       str = (size_t)lda; }
    s += u * 64;
    bf16* d = &lds[((u & 1) * 3 + h) * 8192 + wid * 512];   // wave-uniform
    async_copy16(d, s);
    async_copy16(d + 4096, s + 64 * str);
  };

  // prologue: tile0 complete + B0,B1 of tile1 (A of tile1 issues at t=0,p0).
  STAGE(0, 0); STAGE(0, 1); STAGE(0, 2);
  STAGE(1, 0); STAGE(1, 1);
  asm volatile("s_waitcnt vmcnt(4)" ::: "memory");
  __builtin_amdgcn_s_barrier();

  bf16x8 bfrag[4][2];
  for (int t = 0; t < NT; ++t) {
    const int base = (t & 1) * 24576;
    #pragma unroll
    for (int p = 0; p < 4; ++p) {
      bf16x8 af[2];
      if (p == 0) {
        #pragma unroll
        for (int j = 0; j < 4; ++j) {
          int nn = wc * 64 + j * 16 + fl;                // 0..255
          #pragma unroll
          for (int kk = 0; kk < 2; ++kk) {
            int q = (kk * 4 + fq) ^ (nn & 7);
            bfrag[j][kk] = *(const bf16x8*)&lds[base + (nn >> 7) * 8192 + (nn & 127) * 64 + q * 8];
          }
        }
      }
      {
        int mm = wr * 64 + p * 16 + fl;                  // 0..127
        #pragma unroll
        for (int kk = 0; kk < 2; ++kk) {
          int q = (kk * 4 + fq) ^ (mm & 7);
          af[kk] = *(const bf16x8*)&lds[base + 2 * 8192 + mm * 64 + q * 8];
        }
      }
      if (p == 0)      { if (t + 1 < NT) STAGE(t + 1, 2); }
      else if (p == 1) { if (t + 2 < NT) STAGE(t + 2, 0); }
      else if (p == 2) { if (t + 2 < NT) STAGE(t + 2, 1); }
      if (p == 3) {
        if (t == NT - 2) asm volatile("s_waitcnt vmcnt(0)" ::: "memory");
        else             asm volatile("s_waitcnt vmcnt(4)" ::: "memory");
      }
      __builtin_amdgcn_s_barrier();
      asm volatile("s_waitcnt lgkmcnt(0)" ::: "memory");
      __builtin_amdgcn_sched_barrier(0);
      __builtin_amdgcn_s_setprio(1);
      #pragma unroll
      for (int j = 0; j < 4; ++j)
        #pragma unroll
        for (int kk = 0; kk < 2; ++kk)
          acc[p][j] = __builtin_amdgcn_mfma_f32_16x16x32_bf16(
              af[kk], bfrag[j][kk], acc[p][j], 0, 0, 0);
      __builtin_amdgcn_s_setprio(0);
      __builtin_amdgcn_s_barrier();
    }
  }

  const int mwb = m0 + wr * 64;
  const int nwb = n0 + wc * 64;
  #pragma unroll
  for (int i = 0; i < 4; ++i)
    #pragma unroll
    for (int j = 0; j < 4; ++j)
      #pragma unroll
      for (int r = 0; r < 4; ++r) {
        int m = mwb + i * 16 + fq * 4 + r;
        int n = nwb + j * 16 + fl;
        size_t off = (size_t)m * ldc + n;
        float v = acc[i][j][r];
        if (MODE == 1) ((bf16*)Cout)[off] = (bf16)v;
        else ((float*)Cout)[off] = v + resid[off];
      }
}

// ---------------------------------------------------------------------------
// Fused gu GEMM + SiLU-mul (R4). Block computes the MATCHING g- and u-tiles
// (128x128 each): waves split ws=0 -> g (B rows n0..), ws=1 -> u (B rows
// 2560+n0..). Same 6-slot-ring 8-phase counted-vmcnt schedule as
// gemm128x256 (halves per K-tile: Bg, Bu, A). Epilogue: u-waves park acc in
// LDS (f32, pad 132), one barrier, g-waves emit m = g*sig(g)*u -> mbf.
// Removes the 8192x5120 bf16 gubf round-trip entirely.
// A: 8192x1024 (h2), B: Wt_gu 5120x1024, Mout: 8192x2560 bf16.
__global__ __launch_bounds__(512, 2) void gemm_gusilu(
    const bf16* __restrict__ A, const bf16* __restrict__ B,
    bf16* __restrict__ Mout, int nbx)
{
  __shared__ bf16 lds[49152];          // 96 KiB ring; f32 u-exchange after loop
  const int tid = threadIdx.x, wid = tid >> 6, lane = tid & 63;
  const int cpx = gridDim.x >> 3;
  const int bid = blockIdx.x;
  const int swz = (bid & 7) * cpx + (bid >> 3);
  const int by = swz / nbx, bx = swz - by * nbx;
  const int m0 = by * 128, n0 = bx * 128;      // n0 in g-column space (0..2559)
  const int ws = wid >> 2;                      // 0 = g, 1 = u
  const int wr = (wid >> 1) & 1, wc = wid & 1;  // M-half, N-half (64 each)
  const int fl = lane & 15, fq = lane >> 4;
  const int rloc = wid * 8 + (lane >> 3);
  const int colSwz = ((lane & 7) ^ (lane >> 3)) * 8;
  const int NT = 16, K = 1024;

  fx4 acc[4][4];
  #pragma unroll
  for (int i = 0; i < 4; ++i)
    #pragma unroll
    for (int j = 0; j < 4; ++j) { fx4 z = {0.f, 0.f, 0.f, 0.f}; acc[i][j] = z; }

  const bf16* gA  = A + (size_t)(m0 + rloc) * K + colSwz;
  const bf16* gBg = B + (size_t)(n0 + rloc) * K + colSwz;
  const bf16* gBu = B + (size_t)(2560 + n0 + rloc) * K + colSwz;

  // stage half h (0=Bg, 1=Bu, 2=A) of K-tile u; ring slot = (u&1)*3 + h.
  auto STAGE = [&](int u, int h) {
    const bf16* s = (h == 0) ? gBg : (h == 1) ? gBu : gA;
    s += u * 64;
    bf16* d = &lds[((u & 1) * 3 + h) * 8192 + wid * 512];   // wave-uniform
    async_copy16(d, s);
    async_copy16(d + 4096, s + 64 * K);
  };

  STAGE(0, 0); STAGE(0, 1); STAGE(0, 2);
  STAGE(1, 0); STAGE(1, 1);
  asm volatile("s_waitcnt vmcnt(4)" ::: "memory");
  __builtin_amdgcn_s_barrier();

  bf16x8 bfrag[4][2];
  for (int t = 0; t < NT; ++t) {
    const int base = (t & 1) * 24576;
    #pragma unroll
    for (int p = 0; p < 4; ++p) {
      bf16x8 af[2];
      if (p == 0) {
        #pragma unroll
        for (int j = 0; j < 4; ++j) {
          int nn = wc * 64 + j * 16 + fl;                // 0..127 within half
          #pragma unroll
          for (int kk = 0; kk < 2; ++kk) {
            int q = (kk * 4 + fq) ^ (nn & 7);
            bfrag[j][kk] = *(const bf16x8*)&lds[base + ws * 8192 + nn * 64 + q * 8];
          }
        }
      }
      {
        int mm = wr * 64 + p * 16 + fl;                  // 0..127
        #pragma unroll
        for (int kk = 0; kk < 2; ++kk) {
          int q = (kk * 4 + fq) ^ (mm & 7);
          af[kk] = *(const bf16x8*)&lds[base + 2 * 8192 + mm * 64 + q * 8];
        }
      }
      if (p == 0)      { if (t + 1 < NT) STAGE(t + 1, 2); }
      else if (p == 1) { if (t + 2 < NT) STAGE(t + 2, 0); }
      else if (p == 2) { if (t + 2 < NT) STAGE(t + 2, 1); }
      if (p == 3) {
        if (t == NT - 2) asm volatile("s_waitcnt vmcnt(0)" ::: "memory");
        else             asm volatile("s_waitcnt vmcnt(4)" ::: "memory");
      }
      __builtin_amdgcn_s_barrier();
      asm volatile("s_waitcnt lgkmcnt(0)" ::: "memory");
      __builtin_amdgcn_sched_barrier(0);
      __builtin_amdgcn_s_setprio(1);
      #pragma unroll
      for (int j = 0; j < 4; ++j)
        #pragma unroll
        for (int kk = 0; kk < 2; ++kk)
          acc[p][j] = __builtin_amdgcn_mfma_f32_16x16x32_bf16(
              af[kk], bfrag[j][kk], acc[p][j], 0, 0, 0);
      __builtin_amdgcn_s_setprio(0);
      __builtin_amdgcn_s_barrier();
    }
  }

  // ---- epilogue: u-waves park acc in LDS; g-waves compute g*sig(g)*u ----
  float* uex = (float*)lds;    // 128 x 132 f32 = 67584 B <= 98304 B
  if (ws == 1) {
    #pragma unroll
    for (int i = 0; i < 4; ++i)
      #pragma unroll
      for (int j = 0; j < 4; ++j)
        #pragma unroll
        for (int r = 0; r < 4; ++r) {
          int row = wr * 64 + i * 16 + fq * 4 + r;
          int col = wc * 64 + j * 16 + fl;
          uex[row * 132 + col] = acc[i][j][r];
        }
  }
  __syncthreads();
  if (ws == 0) {
    #pragma unroll
    for (int i = 0; i < 4; ++i)
      #pragma unroll
      for (int j = 0; j < 4; ++j)
        #pragma unroll
        for (int r = 0; r < 4; ++r) {
          int row = wr * 64 + i * 16 + fq * 4 + r;
          int col = wc * 64 + j * 16 + fl;
          float g = acc[i][j][r];
          float u = uex[row * 132 + col];
          Mout[(size_t)(m0 + row) * 2560 + n0 + col] =
              (bf16)(g * sigmoid_f(g) * u);
        }
  }
}

// ---------------------------------------------------------------------------
// Chunk sums of dt*theta: S[(b*64+c)][h*32+d], head-quartered grid (128,4).
__global__ __launch_bounds__(256) void chunk_sum_kernel(
    const float* __restrict__ projT, float* __restrict__ S)
{
  __shared__ float lds[8 * 288];   // 8 rows x (32 dt + 256 theta)
  const int blk = blockIdx.x;      // b*64 + c
  const int hq = blockIdx.y;       // head quarter
  const size_t row0 = (size_t)blk * 64;
  const int tid = threadIdx.x;
  float s = 0.f;
  #pragma unroll 1
  for (int batch = 0; batch < 8; ++batch) {
    __syncthreads();
    const float* src = projT + (row0 + batch * 8) * 1152;
    #pragma unroll
    for (int i = 0; i < 9; ++i) {
      int idx = i * 256 + tid;
      int r = idx / 288, col = idx - r * 288;
      int gcol = (col < 32) ? col : (32 + hq * 256 + (col - 32));
      lds[idx] = src[r * 1152 + gcol];
    }
    __syncthreads();
    int hl = tid >> 5, d = tid & 31;
    #pragma unroll
    for (int r = 0; r < 8; ++r)
      s += lds[r * 288 + hq * 8 + hl] * lds[r * 288 + 32 + hl * 32 + d];
  }
  S[(size_t)blk * 1024 + hq * 256 + tid] = s;
}

// ---------------------------------------------------------------------------
// RoPE apply, one block per (b,c,h).
__global__ __launch_bounds__(256) void rope_kernel(
    bf16* proj, const float* __restrict__ projT, const float* __restrict__ S)
{
  __shared__ float angs[64 * 33], angc[64 * 33];
  const int blk = blockIdx.x;
  const int b = blk >> 11, c = (blk >> 5) & 63, h = blk & 31;
  const size_t t0 = (size_t)b * 4096 + c * 64;
  const int w = threadIdx.x >> 6, lane = threadIdx.x & 63;
  const float* tr = projT + (t0 + lane) * 1152;
  float dtv = tr[h];
  const float* thp = tr + 32 + h * 32 + w * 8;
  float4 th0 = *(const float4*)thp;
  float4 th1 = *(const float4*)(thp + 4);
  const float* Sp = S + (size_t)(b * 64 + lane) * 1024 + h * 32 + w * 8;
  float4 S0 = *(const float4*)Sp;
  float4 S1 = *(const float4*)(Sp + 4);
  float th[8] = { th0.x, th0.y, th0.z, th0.w, th1.x, th1.y, th1.z, th1.w };
  float Sv[8] = { S0.x, S0.y, S0.z, S0.w, S1.x, S1.y, S1.z, S1.w };
  #pragma unroll 1
  for (int j = 0; j < 8; ++j) {
    int d = w * 8 + j;
    float sv = (lane < c) ? Sv[j] : 0.f;
    float off = warp_sum64(sv);
    float v = dtv * th[j];
    #pragma unroll
    for (int o = 1; o < 64; o <<= 1) { float u = __shfl_up(v, o); if (lane >= o) v += u; }
    float ang = off + v;
    float sn, cs;
    sincosf(ang, &sn, &cs);
    angs[lane * 33 + d] = sn;
    angc[lane * 33 + d] = cs;
  }
  __syncthreads();
  const int tt = threadIdx.x >> 2, q = threadIdx.x & 3;
  const size_t base = (t0 + tt) * 8192 + 4096 + h * 64 + q * 16;
  #pragma unroll
  for (int m = 0; m < 2; ++m) {   // m=0: B, m=1: C
    bf16* p = proj + base + m * 2048;
    bf16x8 v0 = *(const bf16x8*)(p);
    bf16x8 v1 = *(const bf16x8*)(p + 8);
    bf16x8 r0, r1;
    #pragma unroll
    for (int pp = 0; pp < 4; ++pp) {
      int d = q * 8 + pp;
      float e1 = (float)v0[2 * pp], e2 = (float)v0[2 * pp + 1];
      float sn = angs[tt * 33 + d], cs = angc[tt * 33 + d];
      r0[2 * pp]     = (bf16)(cs * e1 - sn * e2);
      r0[2 * pp + 1] = (bf16)(sn * e1 + cs * e2);
    }
    #pragma unroll
    for (int pp = 0; pp < 4; ++pp) {
      int d = q * 8 + 4 + pp;
      float e1 = (float)v1[2 * pp], e2 = (float)v1[2 * pp + 1];
      float sn = angs[tt * 33 + d], cs = angc[tt * 33 + d];
      r1[2 * pp]     = (bf16)(cs * e1 - sn * e2);
      r1[2 * pp + 1] = (bf16)(sn * e1 + cs * e2);
    }
    *(bf16x8*)(p) = r0;
    *(bf16x8*)(p + 8) = r1;
  }
}

// ---------------------------------------------------------------------------
// SSD stage 1 (MFMA), one block per (b,c,h) with blk = b*2048+c*32+h.
__global__ __launch_bounds__(256) void ssd1_kernel(
    const bf16* __restrict__ proj, const float* __restrict__ a_buf,
    bf16* __restrict__ Bx, bf16* __restrict__ states,
    float* __restrict__ rowsum, float* __restrict__ expac, float* __restrict__ dchunk)
{
  __shared__ bf16 Xs[64 * 72], Bs[64 * 72];
  __shared__ float acum[64], dsv[64];
  const int blk = blockIdx.x;
  const int h = blk & 31;
  const size_t bs0 = ((size_t)(blk >> 5)) * 64;
  const int tid = threadIdx.x;
  const int l = tid >> 2, p0 = (tid & 3) * 16;
  {
    const bf16* xrow = proj + (bs0 + l) * 8192 + 2048 + h * 64 + p0;
    *(bf16x8*)&Xs[l * 72 + p0]     = ((const bf16x8*)xrow)[0];
    *(bf16x8*)&Xs[l * 72 + p0 + 8] = ((const bf16x8*)xrow)[1];
    const bf16* brow = proj + (bs0 + l) * 8192 + 4096 + h * 64 + p0;
    *(bf16x8*)&Bs[l * 72 + p0]     = ((const bf16x8*)brow)[0];
    *(bf16x8*)&Bs[l * 72 + p0 + 8] = ((const bf16x8*)brow)[1];
  }
  if (tid < 64) {
    float v = a_buf[(bs0 + tid) * 32 + h];
    #pragma unroll
    for (int o = 1; o < 64; o <<= 1) { float u = __shfl_up(v, o); if (tid >= o) v += u; }
    acum[tid] = v;
    float a63 = __shfl(v, 63);
    dsv[tid] = expf(a63 - v);
    expac[(size_t)blk * 64 + tid] = expf(v);
    if (tid == 63) dchunk[blk] = expf(v);
  }
  __syncthreads();
  {
    float al = acum[l];
    float rs = 0.f;
    for (int s = tid & 3; s <= l; s += 4) rs += expf(al - acum[s]);
    rs += __shfl_xor(rs, 1);
    rs += __shfl_xor(rs, 2);
    if ((tid & 3) == 0) rowsum[(size_t)blk * 64 + l] = rs + (float)(63 - l);
  }
  const int wv = tid >> 6, lane = tid & 63;
  const int mi = lane & 15, kq = lane >> 4;
  const int m0 = wv * 16;
  fx4 accB[4], accS[4];
  #pragma unroll
  for (int j4 = 0; j4 < 4; ++j4) { fx4 z = {0.f,0.f,0.f,0.f}; accB[j4] = z; accS[j4] = z; }
  #pragma unroll
  for (int kk = 0; kk < 2; ++kk) {
    const int lb = kk * 32 + kq * 8;
    bf16x8 aX, aXd;
    #pragma unroll
    for (int j = 0; j < 8; ++j) {
      bf16 xv = Xs[(lb + j) * 72 + m0 + mi];
      aX[j] = xv;
      aXd[j] = (bf16)((float)xv * dsv[lb + j]);
    }
    #pragma unroll
    for (int j4 = 0; j4 < 4; ++j4) {
      bf16x8 bB;
      #pragma unroll
      for (int j = 0; j < 8; ++j) bB[j] = Bs[(lb + j) * 72 + j4 * 16 + mi];
      accB[j4] = __builtin_amdgcn_mfma_f32_16x16x32_bf16(aX, bB, accB[j4], 0, 0, 0);
      accS[j4] = __builtin_amdgcn_mfma_f32_16x16x32_bf16(aXd, bB, accS[j4], 0, 0, 0);
    }
  }
  const size_t obase = (size_t)blk * 4096;
  #pragma unroll
  for (int j4 = 0; j4 < 4; ++j4) {
    #pragma unroll
    for (int r = 0; r < 4; ++r) {
      int p = m0 + kq * 4 + r;
      int n = j4 * 16 + mi;
      Bx[obase + p * 64 + n] = (bf16)accB[j4][r];
      states[obase + p * 64 + n] = (bf16)accS[j4][r];
    }
  }
}

// ---------------------------------------------------------------------------
// SSD stage 2: inclusive scan over chunks (f32 carry, bf16 storage).
__global__ __launch_bounds__(128) void ssd2_kernel(
    bf16* __restrict__ states, const float* __restrict__ dchunk)
{
  const int blk = blockIdx.x;  // 1024 = b(2) x h(32) x q(16)
  const int b = blk >> 9, rest = blk & 511;
  const int h = rest >> 4, q = rest & 15;
  const int e0 = q * 256 + threadIdx.x * 2;
  float fs0 = 0.f, fs1 = 0.f;
  #pragma unroll 2
  for (int c = 0; c < 64; ++c) {
    size_t idx = ((size_t)(b * 2048 + c * 32 + h) * 4096) + e0;
    float dec = dchunk[b * 2048 + c * 32 + h];
    bf16x2 st = *(const bf16x2*)(states + idx);
    fs0 = fs0 * dec + (float)st[0];
    fs1 = fs1 * dec + (float)st[1];
    bf16x2 o = { (bf16)fs0, (bf16)fs1 };
    *(bf16x2*)(states + idx) = o;
  }
}

// ---------------------------------------------------------------------------
// SSD stage 3 (MFMA), one block per (b,c,h).
__global__ __launch_bounds__(256) void ssd3_kernel(
    bf16* proj, const bf16* __restrict__ Bx, const bf16* __restrict__ FS,
    const float* __restrict__ rowsum, const float* __restrict__ expac,
    const float* __restrict__ xsum, const float* __restrict__ D_param)
{
  __shared__ bf16 Cs[64 * 72], BxS[64 * 72], FSs[64 * 72];
  __shared__ float rs_s[64], ea_s[64], sk_s[64];
  const int blk = blockIdx.x;
  const int h = blk & 31;
  const size_t bs0 = ((size_t)(blk >> 5)) * 64;
  const int tid = threadIdx.x;
  const int l = tid >> 2, q0 = (tid & 3) * 16;
  {
    const bf16* crow = proj + (bs0 + l) * 8192 + 6144 + h * 64 + q0;
    *(bf16x8*)&Cs[l * 72 + q0]     = ((const bf16x8*)crow)[0];
    *(bf16x8*)&Cs[l * 72 + q0 + 8] = ((const bf16x8*)crow)[1];
    size_t mb = (size_t)blk * 4096 + l * 64 + q0;
    *(bf16x8*)&BxS[l * 72 + q0]     = ((const bf16x8*)(Bx + mb))[0];
    *(bf16x8*)&BxS[l * 72 + q0 + 8] = ((const bf16x8*)(Bx + mb))[1];
    *(bf16x8*)&FSs[l * 72 + q0]     = ((const bf16x8*)(FS + mb))[0];
    *(bf16x8*)&FSs[l * 72 + q0 + 8] = ((const bf16x8*)(FS + mb))[1];
  }
  if (tid < 64) {
    rs_s[tid] = rowsum[(size_t)blk * 64 + tid];
    ea_s[tid] = expac[(size_t)blk * 64 + tid];
    sk_s[tid] = D_param[h] * xsum[(bs0 + tid) * 32 + h];
  }
  __syncthreads();
  const int wv = tid >> 6, lane = tid & 63;
  const int mi = lane & 15, kq = lane >> 4;
  const int m0 = wv * 16;
  fx4 acc1[4], acc2[4];
  #pragma unroll
  for (int j4 = 0; j4 < 4; ++j4) { fx4 z = {0.f,0.f,0.f,0.f}; acc1[j4] = z; acc2[j4] = z; }
  #pragma unroll
  for (int kk = 0; kk < 2; ++kk) {
    bf16x8 aC = *(const bf16x8*)&Cs[(m0 + mi) * 72 + kk * 32 + kq * 8];
    #pragma unroll
    for (int j4 = 0; j4 < 4; ++j4) {
      bf16x8 bx = *(const bf16x8*)&BxS[(j4 * 16 + mi) * 72 + kk * 32 + kq * 8];
      bf16x8 fs = *(const bf16x8*)&FSs[(j4 * 16 + mi) * 72 + kk * 32 + kq * 8];
      acc1[j4] = __builtin_amdgcn_mfma_f32_16x16x32_bf16(aC, bx, acc1[j4], 0, 0, 0);
      acc2[j4] = __builtin_amdgcn_mfma_f32_16x16x32_bf16(aC, fs, acc2[j4], 0, 0, 0);
    }
  }
  #pragma unroll
  for (int j4 = 0; j4 < 4; ++j4) {
    #pragma unroll
    for (int r = 0; r < 4; ++r) {
      int li = m0 + kq * 4 + r;
      int p = j4 * 16 + mi;
      float y = rs_s[li] * acc1[j4][r] + ea_s[li] * acc2[j4][r] + sk_s[li];
      size_t zoff = (bs0 + li) * 8192 + h * 64 + p;
      float z = (float)proj[zoff];
      proj[zoff + 2048] = (bf16)(y * z * sigmoid_f(z));
    }
  }
}

// ---------------------------------------------------------------------------
extern "C" void kernel_launch(void* const* d_in, const int* in_sizes, int n_in,
                              void* d_out, int out_size, void* d_ws, size_t ws_size,
                              hipStream_t stream) {
  (void)in_sizes; (void)n_in; (void)out_size;
  if (ws_size < WS_NEEDED) return;  // diagnostic guard: fail absmax, not SIGABRT
  const float* x       = (const float*)d_in[0];
  const float* n1w     = (const float*)d_in[1];
  const float* n2w     = (const float*)d_in[2];
  const float* W_in    = (const float*)d_in[3];
  const float* W_out   = (const float*)d_in[4];
  const float* A_log   = (const float*)d_in[5];
  const float* D_param = (const float*)d_in[6];
  const float* dt_bias = (const float*)d_in[7];
  const float* B_bias  = (const float*)d_in[8];
  const float* C_bias  = (const float*)d_in[9];
  const float* Bn_w    = (const float*)d_in[10];
  const float* Cn_w    = (const float*)d_in[11];
  const float* Wg      = (const float*)d_in[12];
  const float* Wu      = (const float*)d_in[13];
  const float* Wd      = (const float*)d_in[14];
  float* out = (float*)d_out;
  char* ws = (char*)d_ws;

  bf16*  proj   = (bf16*)(ws + OFF_PROJ);
  float* projT  = (float*)(ws + OFF_PROJT);
  bf16*  h_hi   = (bf16*)(ws + OFF_HHI);
  bf16*  h_lo   = (bf16*)(ws + OFF_HLO);
  bf16*  Wt_in  = (bf16*)(ws + OFF_WTIN);
  bf16*  Wt_hi  = (bf16*)(ws + OFF_WTHI);
  bf16*  Wt_lo  = (bf16*)(ws + OFF_WTLO);
  bf16*  Wt_out = (bf16*)(ws + OFF_WTOUT);
  bf16*  Wt_gu  = (bf16*)(ws + OFF_WTGU);
  bf16*  Wt_d   = (bf16*)(ws + OFF_WTD);
  bf16*  Bx     = (bf16*)(ws + OFF_BX);
  bf16*  states = (bf16*)(ws + OFF_STATES);
  float* a_buf  = (float*)(ws + OFF_ABUF);
  float* xsum_  = (float*)(ws + OFF_XSUM);
  float* rowsum = (float*)(ws + OFF_ROWSUM);
  float* expac  = (float*)(ws + OFF_EXPA);
  float* dchunk = (float*)(ws + OFF_DCHUNK);
  float* gamma_ = (float*)(ws + OFF_GAMMA);
  float* Ssum   = (float*)(ws + OFF_HLO);    // 512KB chunk sums (h_lo dead by then)
  bf16*  ybf    = proj + 2048;               // cols [2048,4096) of proj, lda 8192
  bf16*  mbf    = (bf16*)(ws + OFF_MBF);
  bf16*  h2bf   = h_hi;                      // reuse after proj GEMMs
  float* x2     = out;                       // x2 lives in d_out

  // --- weight transposes needed up-front ---
  transpose_cast<<<dim3(256, 32), 256, 0, stream>>>(W_in, 9248, 0, Wt_in, 1024, 8192);
  transpose_cast_hilo<<<dim3(36, 32), 256, 0, stream>>>(W_in, 9248, 8192, Wt_hi, Wt_lo, 1024, 1056);

  // --- norm1 (hi/lo split for the precision-critical dt/theta tail GEMM) ---
  rmsnorm_kernel<<<8192, 256, 0, stream>>>(x, n1w, h_hi, h_lo);

  // --- in-projection: fused hi/lo tail, then dt, then proj w/ fused prep ---
  gemm_tail<<<dim3(9, 64), 256, 0, stream>>>(h_hi, h_lo, Wt_hi, Wt_lo, projT);
  dt_kernel<<<1024, 256, 0, stream>>>(projT, A_log, dt_bias, a_buf, gamma_);
  gemm_proj256<<<dim3(1024), 512, 0, stream>>>(h_hi, Wt_in, proj, gamma_, xsum_,
                                               Bn_w, Cn_w, B_bias, C_bias);

  // --- hierarchical RoPE ---
  chunk_sum_kernel<<<dim3(128, 4), 256, 0, stream>>>(projT, Ssum);
  rope_kernel<<<4096, 256, 0, stream>>>(proj, projT, Ssum);

  // --- SSD (MFMA) ---
  ssd1_kernel<<<4096, 256, 0, stream>>>(proj, a_buf, Bx, states, rowsum, expac, dchunk);
  ssd2_kernel<<<1024, 128, 0, stream>>>(states, dchunk);
  ssd3_kernel<<<4096, 256, 0, stream>>>(proj, Bx, states, rowsum, expac, xsum_, D_param);

  // --- late weight transposes (overlay dead states region) ---
  transpose_cast<<<dim3(32, 64), 256, 0, stream>>>(W_out, 1024, 0, Wt_out, 2048, 1024);
  transpose_cast<<<dim3(80, 32), 256, 0, stream>>>(Wg, 2560, 0, Wt_gu, 1024, 2560);
  transpose_cast<<<dim3(80, 32), 256, 0, stream>>>(Wu, 2560, 0, Wt_gu + (size_t)2560 * 1024, 1024, 2560);
  transpose_cast<<<dim3(32, 80), 256, 0, stream>>>(Wd, 1024, 0, Wt_d, 2560, 1024);

  // --- out-projection + residual (x2 -> d_out) ---
  // M=8192, N=1024, K=2048 -> grid 64x4 = 256 blocks = exactly 1 round.
  gemm128x256<2><<<dim3(256), 512, 0, stream>>>(ybf, Wt_out, x2, x, 32, 8192, 1024, 4);

  // --- MLP ---
  rmsnorm_kernel<<<8192, 256, 0, stream>>>(x2, n2w, h2bf, nullptr);
  // fused gu GEMM + SiLU: M=8192, g/u cols 2560 -> grid 64x20 = 1280 blocks
  // (= 5 exact rounds), writes mbf directly (no gubf round-trip).
  gemm_gusilu<<<dim3(1280), 512, 0, stream>>>(h2bf, Wt_gu, mbf, 20);
  // down: M=8192, N=1024, K=2560 -> grid 64x4 = 256 blocks = exactly 1 round.
  gemm128x256<2><<<dim3(256), 512, 0, stream>>>(mbf, Wt_d, out, x2, 40, 2560, 1024, 4);
}

// Round 6
// 734.708 us; speedup vs baseline: 1.1321x; 1.0096x over previous
//
#include <hip/hip_runtime.h>
#include <cstdint>
#include <cmath>

// ---------------------------------------------------------------------------
// Mamba3 block forward, MI355X (gfx950).
// B=2, S=4096 (8192 tokens), D_MODEL=1024, D_INNER=2048, NHEADS=32, HD=64,
// D_STATE=64, CHUNK=64, D_MLP=2560, PROJ=9248.
// Workspace budget: ~251.5 MiB. x2 lives in d_out.
//
// R1: gemm_proj -> 256^2 8-phase counted-vmcnt schedule: 207 -> 162 us.
// R2: gu on 256^2 tiles REGRESSED (grid quantization: 640 blk = 2.5 rounds).
// R3: BM=128xBN=256 8-phase variant, exact-round grids: 832 -> 783.
// R4/R5: gusilu fusion (gubf round-trip removed) + vmcnt drain fix: -> 742.
// R6: gemm_tail regrid BN=128->192: old grid 576 blk @ 2/CU (512 slots) =
//     2 effective rounds (same quantization bug as R2); new grid 64x6=384
//     blk = EXACT single round @ 80KB LDS / 2 blk/CU. Same 2-barrier
//     structure, same K/product order (bit-identical). dt_kernel fused into
//     the tail epilogue (n<32 threads; f32 round-trip was lossless).
// ---------------------------------------------------------------------------

typedef __bf16 bf16;
typedef __bf16 bf16x2 __attribute__((ext_vector_type(2)));
typedef __bf16 bf16x4 __attribute__((ext_vector_type(4)));
typedef __bf16 bf16x8 __attribute__((ext_vector_type(8)));
typedef float fx4 __attribute__((ext_vector_type(4)));

#define DEV __device__ __forceinline__

// ---- workspace layout (bytes) ---------------------------------------------
#define OFF_PROJ    0ull
#define OFF_HHI     134217728ull   // 8192x1024 bf16 (h hi) ; later h2_bf
#define OFF_HLO     150994944ull   // 8192x1024 bf16 (h lo) ; later S (chunk sums, 512KB)
#define OFF_WTIN    167772160ull   // 8192x1024 bf16
#define OFF_WTHI    184549376ull   // 1152x1024 bf16
#define OFF_WTLO    186908672ull   // 1152x1024 bf16
#define OFF_PROJT   189267968ull   // 8192x1152 f32 (dt,theta) -- dead after rope
#define OFF_BX      189267968ull   // 4096x4096 bf16 (written at ssd1, overlays projT)
#define OFF_STATES  222822400ull   // 4096x4096 bf16 -> FS in place; dead after ssd3
#define OFF_WTOUT   222822400ull   // 1024x2048 bf16 (after ssd3, overlays states)
#define OFF_WTGU    227016704ull   // 5120x1024 bf16 (after ssd3)
#define OFF_WTD     237502464ull   // 1024x2560 bf16 (after ssd3)
#define OFF_ABUF    256376832ull   // 8192x32 f32 (per-token A)
#define OFF_XSUM    257425408ull   // 8192x32 f32
#define OFF_ROWSUM  258473984ull   // (2,64,32,64) f32
#define OFF_EXPA    260571136ull   // (2,64,32,64) f32
#define OFF_DCHUNK  262668288ull   // (2,64,32) f32
#define OFF_GAMMA   262684672ull   // 8192x32 f32
#define WS_NEEDED   263733248ull

#define OFF_MBF     83886080ull

// ---------------------------------------------------------------------------
DEV void async_copy16(void* lds, const void* gptr) {
  __builtin_amdgcn_global_load_lds(
      (const __attribute__((address_space(1))) unsigned int*)(gptr),
      (__attribute__((address_space(3))) unsigned int*)(lds),
      16, 0, 0);
}

DEV float warp_sum64(float v) {
  #pragma unroll
  for (int o = 32; o; o >>= 1) v += __shfl_xor(v, o);
  return v;
}

DEV float red16(float v) {   // reduce across 16-lane groups (cc dimension)
  v += __shfl_xor(v, 1); v += __shfl_xor(v, 2);
  v += __shfl_xor(v, 4); v += __shfl_xor(v, 8);
  return v;
}

DEV float softplus_f(float x) { return x > 20.f ? x : log1pf(expf(x)); }
DEV float sigmoid_f(float x) { return 1.f / (1.f + expf(-x)); }

// ---------------------------------------------------------------------------
__global__ __launch_bounds__(256) void transpose_cast(
    const float* __restrict__ src, int ld, int col0,
    bf16* __restrict__ dst, int R, int C)
{
  __shared__ float tile[32][33];
  const int c0 = blockIdx.x * 32, r0 = blockIdx.y * 32;
  const int tx = threadIdx.x & 31, ty = threadIdx.x >> 5;
  #pragma unroll
  for (int ii = 0; ii < 4; ++ii) {
    int i = ty + ii * 8;
    int c = c0 + tx;
    tile[i][tx] = (c < C) ? src[(size_t)(r0 + i) * ld + col0 + c] : 0.f;
  }
  __syncthreads();
  #pragma unroll
  for (int ii = 0; ii < 4; ++ii) {
    int i = ty + ii * 8;
    dst[(size_t)(c0 + i) * R + r0 + tx] = (bf16)tile[tx][i];
  }
}

__global__ __launch_bounds__(256) void transpose_cast_hilo(
    const float* __restrict__ src, int ld, int col0,
    bf16* __restrict__ dhi, bf16* __restrict__ dlo, int R, int C)
{
  __shared__ float tile[32][33];
  const int c0 = blockIdx.x * 32, r0 = blockIdx.y * 32;
  const int tx = threadIdx.x & 31, ty = threadIdx.x >> 5;
  #pragma unroll
  for (int ii = 0; ii < 4; ++ii) {
    int i = ty + ii * 8;
    int c = c0 + tx;
    tile[i][tx] = (c < C) ? src[(size_t)(r0 + i) * ld + col0 + c] : 0.f;
  }
  __syncthreads();
  #pragma unroll
  for (int ii = 0; ii < 4; ++ii) {
    int i = ty + ii * 8;
    float v = tile[tx][i];
    bf16 hi = (bf16)v;
    size_t o = (size_t)(c0 + i) * R + r0 + tx;
    dhi[o] = hi;
    dlo[o] = (bf16)(v - (float)hi);
  }
}

// ---------------------------------------------------------------------------
__global__ __launch_bounds__(256) void rmsnorm_kernel(
    const float* __restrict__ x, const float* __restrict__ w,
    bf16* __restrict__ hi, bf16* __restrict__ lo)
{
  __shared__ float red[4];
  const size_t row = blockIdx.x;
  const int tid = threadIdx.x;
  float4 v = ((const float4*)(x + row * 1024))[tid];
  float ss = v.x * v.x + v.y * v.y + v.z * v.z + v.w * v.w;
  ss = warp_sum64(ss);
  if ((tid & 63) == 0) red[tid >> 6] = ss;
  __syncthreads();
  float tot = red[0] + red[1] + red[2] + red[3];
  float s = rsqrtf(tot * (1.f / 1024.f) + 1e-5f);
  float4 wv = ((const float4*)w)[tid];
  float h0 = v.x * s * wv.x, h1 = v.y * s * wv.y, h2 = v.z * s * wv.z, h3 = v.w * s * wv.w;
  bf16x4 hv = { (bf16)h0, (bf16)h1, (bf16)h2, (bf16)h3 };
  *(bf16x4*)(hi + row * 1024 + tid * 4) = hv;
  if (lo) {
    bf16x4 lv = { (bf16)(h0 - (float)hv[0]), (bf16)(h1 - (float)hv[1]),
                  (bf16)(h2 - (float)hv[2]), (bf16)(h3 - (float)hv[3]) };
    *(bf16x4*)(lo + row * 1024 + tid * 4) = lv;
  }
}

// ---------------------------------------------------------------------------
// Fused hi/lo tail GEMM (R6): out = Ahi*Whi^T + Ahi*Wlo^T + Alo*Whi^T, f32.
// M=8192, N=1152, K=1024, ldc=1152. BM=128, BN=192 -> grid 64x6 = 384 blocks
// at 80KB LDS / 2 blk/CU (512 slots) = EXACT single round (old BN=128 grid
// was 576 blocks -> 2 effective rounds). Same 2-barrier schedule; same
// per-element K/product order as the BN=128 version (bit-identical).
// Epilogue additionally performs the dt transform for n<32 (old dt_kernel):
// writes softplus'd dt to Cout, and a/gamma to a_buf/gamma_buf.
__global__ __launch_bounds__(256, 2) void gemm_tail(
    const bf16* Ahi, const bf16* Alo, const bf16* Whi, const bf16* Wlo,
    float* Cout,
    const float* __restrict__ A_log, const float* __restrict__ dt_bias,
    float* __restrict__ a_buf, float* __restrict__ gamma_buf)
{
  __shared__ bf16 Ah[128 * 64], Al[128 * 64];    // 16 KB each
  __shared__ bf16 Bh[192 * 64], Bl[192 * 64];    // 24 KB each -> 80 KB total
  const int tid = threadIdx.x, wid = tid >> 6, lane = tid & 63;
  const int m0 = blockIdx.y * 128, n0 = blockIdx.x * 192;
  const int wm = (wid & 1) * 64, wn = (wid >> 1) * 96;   // waves 2M x 2N
  fx4 acc[4][6];
  #pragma unroll
  for (int i = 0; i < 4; ++i)
    #pragma unroll
    for (int j = 0; j < 6; ++j) { fx4 z = {0.f, 0.f, 0.f, 0.f}; acc[i][j] = z; }

  const int rsub = lane >> 3;          // 0..7 (row within 8-row group)
  const int slot = lane & 7;
  const int colSwz = ((slot ^ rsub) * 8);   // row&7 == rsub for all issues

  for (int k0 = 0; k0 < 1024; k0 += 64) {
    __syncthreads();
    // A hi/lo: 4 issues x 32 rows (wave covers 8 rows per issue)
    #pragma unroll
    for (int i = 0; i < 4; ++i) {
      int row = i * 32 + wid * 8 + rsub;
      size_t ao = (size_t)(m0 + row) * 1024 + k0 + colSwz;
      async_copy16(&Ah[i * 2048 + wid * 512], Ahi + ao);
      async_copy16(&Al[i * 2048 + wid * 512], Alo + ao);
    }
    // B hi/lo: 6 issues x 32 rows
    #pragma unroll
    for (int i = 0; i < 6; ++i) {
      int row = i * 32 + wid * 8 + rsub;
      size_t bo = (size_t)(n0 + row) * 1024 + k0 + colSwz;
      async_copy16(&Bh[i * 2048 + wid * 512], Whi + bo);
      async_copy16(&Bl[i * 2048 + wid * 512], Wlo + bo);
    }
    __syncthreads();   // compiler drains vmcnt before barrier (verified pattern)
    #pragma unroll
    for (int kk = 0; kk < 2; ++kk) {
      bf16x8 ah[4], al[4], bh[6], bl[6];
      #pragma unroll
      for (int i = 0; i < 4; ++i) {
        int mm = wm + i * 16 + (lane & 15);
        int sA = (kk * 4 + (lane >> 4)) ^ (mm & 7);
        ah[i] = *(const bf16x8*)&Ah[mm * 64 + sA * 8];
        al[i] = *(const bf16x8*)&Al[mm * 64 + sA * 8];
      }
      #pragma unroll
      for (int j = 0; j < 6; ++j) {
        int nn = wn + j * 16 + (lane & 15);
        int sB = (kk * 4 + (lane >> 4)) ^ (nn & 7);
        bh[j] = *(const bf16x8*)&Bh[nn * 64 + sB * 8];
        bl[j] = *(const bf16x8*)&Bl[nn * 64 + sB * 8];
      }
      #pragma unroll
      for (int i = 0; i < 4; ++i)
        #pragma unroll
        for (int j = 0; j < 6; ++j) {
          acc[i][j] = __builtin_amdgcn_mfma_f32_16x16x32_bf16(ah[i], bh[j], acc[i][j], 0, 0, 0);
          acc[i][j] = __builtin_amdgcn_mfma_f32_16x16x32_bf16(ah[i], bl[j], acc[i][j], 0, 0, 0);
          acc[i][j] = __builtin_amdgcn_mfma_f32_16x16x32_bf16(al[i], bh[j], acc[i][j], 0, 0, 0);
        }
    }
  }
  const int r0 = (lane >> 4) * 4, cc = lane & 15;
  #pragma unroll
  for (int i = 0; i < 4; ++i)
    #pragma unroll
    for (int j = 0; j < 6; ++j)
      #pragma unroll
      for (int r = 0; r < 4; ++r) {
        int m = m0 + wm + i * 16 + r0 + r;
        int n = n0 + wn + j * 16 + cc;
        float v = acc[i][j][r];
        if (n < 32) {
          // fused dt transform (old dt_kernel; acc f32 == projT round-trip)
          float dt = softplus_f(v + dt_bias[n]);
          float a = -expf(A_log[n]) * dt;
          float alpha = expf(a);
          float gamma = (alpha - 1.f) / (a + 1e-6f) * 0.5f + 1.f;
          a_buf[(size_t)m * 32 + n] = a;
          gamma_buf[(size_t)m * 32 + n] = gamma;
          v = dt;
        }
        Cout[(size_t)m * 1152 + n] = v;
      }
}

// ---------------------------------------------------------------------------
// Proj GEMM, 256x256 tile, 8-phase counted-vmcnt schedule (HK/m201 template),
// with the fused per-region epilogue:
//   z[0,2048): plain bf16 store
//   x[2048,4096): xsum (row-sum over head) then *gamma
//   B[4096,6144): rmsnorm(row)*Bn_w + B_bias ; C[6144,8192): same w/ Cn_w
__global__ __launch_bounds__(512, 2) void gemm_proj256(
    const bf16* __restrict__ A, const bf16* __restrict__ B, bf16* __restrict__ Cout,
    const float* __restrict__ gamma_buf, float* __restrict__ xsum,
    const float* __restrict__ Bn_w, const float* __restrict__ Cn_w,
    const float* __restrict__ B_bias, const float* __restrict__ C_bias)
{
  __shared__ bf16 lds[65536];          // 128 KiB: 8 half-slots x 8192 elems
  const int tid = threadIdx.x, wid = tid >> 6, lane = tid & 63;
  const int bid = blockIdx.x;
  const int swz = (bid & 7) * 128 + (bid >> 3);
  const int by = swz >> 5, bx = swz & 31;     // 32x32 tiles of 256
  const int m0 = by * 256, n0 = bx * 256;
  const int wr = wid >> 2, wc = wid & 3;      // wave -> (2M x 4N)
  const int fl = lane & 15, fq = lane >> 4;   // fragment lane coords
  const int rloc = wid * 8 + (lane >> 3);
  const int colSwz = ((lane & 7) ^ (lane >> 3)) * 8;

  fx4 acc[8][4];
  #pragma unroll
  for (int i = 0; i < 8; ++i)
    #pragma unroll
    for (int j = 0; j < 4; ++j) { fx4 z = {0.f, 0.f, 0.f, 0.f}; acc[i][j] = z; }

  const bf16* gA = A + (size_t)(m0 + rloc) * 1024 + colSwz;
  const bf16* gB = B + (size_t)(n0 + rloc) * 1024 + colSwz;

  // stage half h (0=B0,1=B1,2=A0,3=A1) of K-tile u; LDS slot = (4u+h) & 7.
  auto STAGE = [&](int u, int h) {
    const bf16* s = (h < 2) ? gB : gA;
    s += (size_t)(h & 1) * 128 * 1024 + u * 64;
    bf16* d = &lds[((u & 1) * 4 + h) * 8192 + wid * 512];   // wave-uniform
    async_copy16(d, s);
    async_copy16(d + 4096, s + 64 * 1024);
  };

  STAGE(0, 0); STAGE(0, 1); STAGE(0, 2); STAGE(0, 3);
  STAGE(1, 0); STAGE(1, 1);
  asm volatile("s_waitcnt vmcnt(4)" ::: "memory");
  __builtin_amdgcn_s_barrier();

  const int NT = 16;                    // K = 1024
  bf16x8 bfrag[4][2];
  for (int t = 0; t < NT; ++t) {
    const int Bb = (t & 1) * 32768;     // B-tile element base
    const int Ab = Bb + 16384;          // A-tile element base
    #pragma unroll
    for (int p = 0; p < 4; ++p) {
      bf16x8 af[2][2];
      if (p == 0) {
        #pragma unroll
        for (int j = 0; j < 4; ++j) {
          int nn = wc * 64 + j * 16 + fl;
          #pragma unroll
          for (int kk = 0; kk < 2; ++kk) {
            int q = (kk * 4 + fq) ^ (nn & 7);
            bfrag[j][kk] = *(const bf16x8*)&lds[Bb + nn * 64 + q * 8];
          }
        }
      }
      #pragma unroll
      for (int ii = 0; ii < 2; ++ii) {
        int mm = wr * 128 + (p * 2 + ii) * 16 + fl;
        #pragma unroll
        for (int kk = 0; kk < 2; ++kk) {
          int q = (kk * 4 + fq) ^ (mm & 7);
          af[ii][kk] = *(const bf16x8*)&lds[Ab + mm * 64 + q * 8];
        }
      }
      {
        int H = 4 * t + 6 + p;
        if (H < 4 * NT) STAGE(H >> 2, H & 3);
      }
      // counted vmcnt once per K-tile; full drain at t==NT-2 so the final
      // tile's A-halves are guaranteed resident before t==NT-1 reads them.
      if (p == 3) {
        if (t == NT - 2) asm volatile("s_waitcnt vmcnt(0)" ::: "memory");
        else             asm volatile("s_waitcnt vmcnt(4)" ::: "memory");
      }
      __builtin_amdgcn_s_barrier();
      asm volatile("s_waitcnt lgkmcnt(0)" ::: "memory");
      __builtin_amdgcn_sched_barrier(0);
      __builtin_amdgcn_s_setprio(1);
      #pragma unroll
      for (int ii = 0; ii < 2; ++ii)
        #pragma unroll
        for (int j = 0; j < 4; ++j)
          #pragma unroll
          for (int kk = 0; kk < 2; ++kk)
            acc[p * 2 + ii][j] = __builtin_amdgcn_mfma_f32_16x16x32_bf16(
                af[ii][kk], bfrag[j][kk], acc[p * 2 + ii][j], 0, 0, 0);
      __builtin_amdgcn_s_setprio(0);
      __builtin_amdgcn_s_barrier();
    }
  }

  // ---- fused epilogue ----
  const int reg = bx >> 3;                       // 0=z 1=x 2=B 3=C
  const int hh = ((n0 + wc * 64) & 2047) >> 6;   // head for this wave
  const int mwb = m0 + wr * 128;
  const int nwb = n0 + wc * 64;
  if (reg == 0) {
    #pragma unroll
    for (int i = 0; i < 8; ++i)
      #pragma unroll
      for (int j = 0; j < 4; ++j)
        #pragma unroll
        for (int r = 0; r < 4; ++r) {
          int m = mwb + i * 16 + fq * 4 + r;
          int n = nwb + j * 16 + fl;
          Cout[(size_t)m * 8192 + n] = (bf16)acc[i][j][r];
        }
  } else if (reg == 1) {
    #pragma unroll
    for (int i = 0; i < 8; ++i)
      #pragma unroll
      for (int r = 0; r < 4; ++r) {
        float s = acc[i][0][r] + acc[i][1][r] + acc[i][2][r] + acc[i][3][r];
        s = red16(s);
        int m = mwb + i * 16 + fq * 4 + r;
        if (fl == 0) xsum[(size_t)m * 32 + hh] = s;
        float g = gamma_buf[(size_t)m * 32 + hh];
        #pragma unroll
        for (int j = 0; j < 4; ++j) {
          int n = nwb + j * 16 + fl;
          Cout[(size_t)m * 8192 + n] = (bf16)(acc[i][j][r] * g);
        }
      }
  } else {
    const float* w = (reg == 2) ? Bn_w : Cn_w;
    const float* bias = (reg == 2) ? B_bias : C_bias;
    #pragma unroll
    for (int i = 0; i < 8; ++i)
      #pragma unroll
      for (int r = 0; r < 4; ++r) {
        float ss = acc[i][0][r] * acc[i][0][r] + acc[i][1][r] * acc[i][1][r]
                 + acc[i][2][r] * acc[i][2][r] + acc[i][3][r] * acc[i][3][r];
        ss = red16(ss);
        float sc = rsqrtf(ss * (1.f / 64.f) + 1e-5f);
        int m = mwb + i * 16 + fq * 4 + r;
        #pragma unroll
        for (int j = 0; j < 4; ++j) {
          int c = j * 16 + fl;
          Cout[(size_t)m * 8192 + nwb + c] =
              (bf16)(acc[i][j][r] * sc * w[c] + bias[hh * 64 + c]);
        }
      }
  }
}

// ---------------------------------------------------------------------------
// Generic 128x256-tile 8-phase GEMM, same counted-vmcnt schedule as
// gemm_proj256 (harness-verified); parameter variant: BM=128, BN=256, BK=64.
// LDS = 6-slot ring x 16KB = 96 KiB (3 halves per K-tile: B0,B1,A).
// Issue plan per K-tile t: p0 -> A(t+1), p1 -> B0(t+2), p2 -> B1(t+2),
// p3 -> vmcnt(4) => tile t+1 landed; vmcnt(0) at t==NT-2 (drain fix).
// C = A(MxK, lda) * B^T(NxK). MODE 1 = bf16 store, MODE 2 = f32 + resid.
// Requirements: M%128==0, N%256==0, K%64==0, grid%8==0.
template <int MODE>
__global__ __launch_bounds__(512, 2) void gemm128x256(
    const bf16* __restrict__ A, const bf16* __restrict__ B, void* __restrict__ Cout,
    const float* __restrict__ resid, int NT, int lda, int ldc, int nbx)
{
  __shared__ bf16 lds[49152];          // 96 KiB: 6 half-slots x 8192 elems
  const int tid = threadIdx.x, wid = tid >> 6, lane = tid & 63;
  const int cpx = gridDim.x >> 3;
  const int bid = blockIdx.x;
  const int swz = (bid & 7) * cpx + (bid >> 3);
  const int by = swz / nbx, bx = swz - by * nbx;
  const int m0 = by * 128, n0 = bx * 256;
  const int wr = wid >> 2, wc = wid & 3;       // wave -> (2M x 4N), 64x64 each
  const int fl = lane & 15, fq = lane >> 4;
  const int rloc = wid * 8 + (lane >> 3);      // 0..63
  const int colSwz = ((lane & 7) ^ (lane >> 3)) * 8;
  const int K = NT * 64;

  fx4 acc[4][4];
  #pragma unroll
  for (int i = 0; i < 4; ++i)
    #pragma unroll
    for (int j = 0; j < 4; ++j) { fx4 z = {0.f, 0.f, 0.f, 0.f}; acc[i][j] = z; }

  const bf16* gA = A + (size_t)(m0 + rloc) * lda + colSwz;
  const bf16* gB = B + (size_t)(n0 + rloc) * K + colSwz;

  // stage half h (0=B rows 0-127, 1=B rows 128-255, 2=A rows 0-127) of tile u.
  auto STAGE = [&](int u, int h) {
    const bf16* s;
    size_t str;
    if (h < 2) { s = gB + (size_t)h * 128 * K; str = (size_t)K; }
    else       { s = gA;                       str = (size_t)lda; }
    s += u * 64;
    bf16* d = &lds[((u & 1) * 3 + h) * 8192 + wid * 512];   // wave-uniform
    async_copy16(d, s);
    async_copy16(d + 4096, s + 64 * str);
  };

  // prologue: tile0 complete + B0,B1 of tile1 (A of tile1 issues at t=0,p0).
  STAGE(0, 0); STAGE(0, 1); STAGE(0, 2);
  STAGE(1, 0); STAGE(1, 1);
  asm volatile("s_waitcnt vmcnt(4)" ::: "memory");
  __builtin_amdgcn_s_barrier();

  bf16x8 bfrag[4][2];
  for (int t = 0; t < NT; ++t) {
    const int base = (t & 1) * 24576;
    #pragma unroll
    for (int p = 0; p < 4; ++p) {
      bf16x8 af[2];
      if (p == 0) {
        #pragma unroll
        for (int j = 0; j < 4; ++j) {
          int nn = wc * 64 + j * 16 + fl;                // 0..255
          #pragma unroll
          for (int kk = 0; kk < 2; ++kk) {
            int q = (kk * 4 + fq) ^ (nn & 7);
            bfrag[j][kk] = *(const bf16x8*)&lds[base + (nn >> 7) * 8192 + (nn & 127) * 64 + q * 8];
          }
        }
      }
      {
        int mm = wr * 64 + p * 16 + fl;                  // 0..127
        #pragma unroll
        for (int kk = 0; kk < 2; ++kk) {
          int q = (kk * 4 + fq) ^ (mm & 7);
          af[kk] = *(const bf16x8*)&lds[base + 2 * 8192 + mm * 64 + q * 8];
        }
      }
      if (p == 0)      { if (t + 1 < NT) STAGE(t + 1, 2); }
      else if (p == 1) { if (t + 2 < NT) STAGE(t + 2, 0); }
      else if (p == 2) { if (t + 2 < NT) STAGE(t + 2, 1); }
      if (p == 3) {
        if (t == NT - 2) asm volatile("s_waitcnt vmcnt(0)" ::: "memory");
        else             asm volatile("s_waitcnt vmcnt(4)" ::: "memory");
      }
      __builtin_amdgcn_s_barrier();
      asm volatile("s_waitcnt lgkmcnt(0)" ::: "memory");
      __builtin_amdgcn_sched_barrier(0);
      __builtin_amdgcn_s_setprio(1);
      #pragma unroll
      for (int j = 0; j < 4; ++j)
        #pragma unroll
        for (int kk = 0; kk < 2; ++kk)
          acc[p][j] = __builtin_amdgcn_mfma_f32_16x16x32_bf16(
              af[kk], bfrag[j][kk], acc[p][j], 0, 0, 0);
      __builtin_amdgcn_s_setprio(0);
      __builtin_amdgcn_s_barrier();
    }
  }

  const int mwb = m0 + wr * 64;
  const int nwb = n0 + wc * 64;
  #pragma unroll
  for (int i = 0; i < 4; ++i)
    #pragma unroll
    for (int j = 0; j < 4; ++j)
      #pragma unroll
      for (int r = 0; r < 4; ++r) {
        int m = mwb + i * 16 + fq * 4 + r;
        int n = nwb + j * 16 + fl;
        size_t off = (size_t)m * ldc + n;
        float v = acc[i][j][r];
        if (MODE == 1) ((bf16*)Cout)[off] = (bf16)v;
        else ((float*)Cout)[off] = v + resid[off];
      }
}

// ---------------------------------------------------------------------------
// Fused gu GEMM + SiLU-mul (R4). Block computes the MATCHING g- and u-tiles
// (128x128 each): waves split ws=0 -> g (B rows n0..), ws=1 -> u (B rows
// 2560+n0..). Same 6-slot-ring 8-phase counted-vmcnt schedule as
// gemm128x256 (halves per K-tile: Bg, Bu, A). Epilogue: u-waves park acc in
// LDS (f32, pad 132), one barrier, g-waves emit m = g*sig(g)*u -> mbf.
// Removes the 8192x5120 bf16 gubf round-trip entirely.
// A: 8192x1024 (h2), B: Wt_gu 5120x1024, Mout: 8192x2560 bf16.
__global__ __launch_bounds__(512, 2) void gemm_gusilu(
    const bf16* __restrict__ A, const bf16* __restrict__ B,
    bf16* __restrict__ Mout, int nbx)
{
  __shared__ bf16 lds[49152];          // 96 KiB ring; f32 u-exchange after loop
  const int tid = threadIdx.x, wid = tid >> 6, lane = tid & 63;
  const int cpx = gridDim.x >> 3;
  const int bid = blockIdx.x;
  const int swz = (bid & 7) * cpx + (bid >> 3);
  const int by = swz / nbx, bx = swz - by * nbx;
  const int m0 = by * 128, n0 = bx * 128;      // n0 in g-column space (0..2559)
  const int ws = wid >> 2;                      // 0 = g, 1 = u
  const int wr = (wid >> 1) & 1, wc = wid & 1;  // M-half, N-half (64 each)
  const int fl = lane & 15, fq = lane >> 4;
  const int rloc = wid * 8 + (lane >> 3);
  const int colSwz = ((lane & 7) ^ (lane >> 3)) * 8;
  const int NT = 16, K = 1024;

  fx4 acc[4][4];
  #pragma unroll
  for (int i = 0; i < 4; ++i)
    #pragma unroll
    for (int j = 0; j < 4; ++j) { fx4 z = {0.f, 0.f, 0.f, 0.f}; acc[i][j] = z; }

  const bf16* gA  = A + (size_t)(m0 + rloc) * K + colSwz;
  const bf16* gBg = B + (size_t)(n0 + rloc) * K + colSwz;
  const bf16* gBu = B + (size_t)(2560 + n0 + rloc) * K + colSwz;

  // stage half h (0=Bg, 1=Bu, 2=A) of K-tile u; ring slot = (u&1)*3 + h.
  auto STAGE = [&](int u, int h) {
    const bf16* s = (h == 0) ? gBg : (h == 1) ? gBu : gA;
    s += u * 64;
    bf16* d = &lds[((u & 1) * 3 + h) * 8192 + wid * 512];   // wave-uniform
    async_copy16(d, s);
    async_copy16(d + 4096, s + 64 * K);
  };

  STAGE(0, 0); STAGE(0, 1); STAGE(0, 2);
  STAGE(1, 0); STAGE(1, 1);
  asm volatile("s_waitcnt vmcnt(4)" ::: "memory");
  __builtin_amdgcn_s_barrier();

  bf16x8 bfrag[4][2];
  for (int t = 0; t < NT; ++t) {
    const int base = (t & 1) * 24576;
    #pragma unroll
    for (int p = 0; p < 4; ++p) {
      bf16x8 af[2];
      if (p == 0) {
        #pragma unroll
        for (int j = 0; j < 4; ++j) {
          int nn = wc * 64 + j * 16 + fl;                // 0..127 within half
          #pragma unroll
          for (int kk = 0; kk < 2; ++kk) {
            int q = (kk * 4 + fq) ^ (nn & 7);
            bfrag[j][kk] = *(const bf16x8*)&lds[base + ws * 8192 + nn * 64 + q * 8];
          }
        }
      }
      {
        int mm = wr * 64 + p * 16 + fl;                  // 0..127
        #pragma unroll
        for (int kk = 0; kk < 2; ++kk) {
          int q = (kk * 4 + fq) ^ (mm & 7);
          af[kk] = *(const bf16x8*)&lds[base + 2 * 8192 + mm * 64 + q * 8];
        }
      }
      if (p == 0)      { if (t + 1 < NT) STAGE(t + 1, 2); }
      else if (p == 1) { if (t + 2 < NT) STAGE(t + 2, 0); }
      else if (p == 2) { if (t + 2 < NT) STAGE(t + 2, 1); }
      if (p == 3) {
        if (t == NT - 2) asm volatile("s_waitcnt vmcnt(0)" ::: "memory");
        else             asm volatile("s_waitcnt vmcnt(4)" ::: "memory");
      }
      __builtin_amdgcn_s_barrier();
      asm volatile("s_waitcnt lgkmcnt(0)" ::: "memory");
      __builtin_amdgcn_sched_barrier(0);
      __builtin_amdgcn_s_setprio(1);
      #pragma unroll
      for (int j = 0; j < 4; ++j)
        #pragma unroll
        for (int kk = 0; kk < 2; ++kk)
          acc[p][j] = __builtin_amdgcn_mfma_f32_16x16x32_bf16(
              af[kk], bfrag[j][kk], acc[p][j], 0, 0, 0);
      __builtin_amdgcn_s_setprio(0);
      __builtin_amdgcn_s_barrier();
    }
  }

  // ---- epilogue: u-waves park acc in LDS; g-waves compute g*sig(g)*u ----
  float* uex = (float*)lds;    // 128 x 132 f32 = 67584 B <= 98304 B
  if (ws == 1) {
    #pragma unroll
    for (int i = 0; i < 4; ++i)
      #pragma unroll
      for (int j = 0; j < 4; ++j)
        #pragma unroll
        for (int r = 0; r < 4; ++r) {
          int row = wr * 64 + i * 16 + fq * 4 + r;
          int col = wc * 64 + j * 16 + fl;
          uex[row * 132 + col] = acc[i][j][r];
        }
  }
  __syncthreads();
  if (ws == 0) {
    #pragma unroll
    for (int i = 0; i < 4; ++i)
      #pragma unroll
      for (int j = 0; j < 4; ++j)
        #pragma unroll
        for (int r = 0; r < 4; ++r) {
          int row = wr * 64 + i * 16 + fq * 4 + r;
          int col = wc * 64 + j * 16 + fl;
          float g = acc[i][j][r];
          float u = uex[row * 132 + col];
          Mout[(size_t)(m0 + row) * 2560 + n0 + col] =
              (bf16)(g * sigmoid_f(g) * u);
        }
  }
}

// ---------------------------------------------------------------------------
// Chunk sums of dt*theta: S[(b*64+c)][h*32+d], head-quartered grid (128,4).
__global__ __launch_bounds__(256) void chunk_sum_kernel(
    const float* __restrict__ projT, float* __restrict__ S)
{
  __shared__ float lds[8 * 288];   // 8 rows x (32 dt + 256 theta)
  const int blk = blockIdx.x;      // b*64 + c
  const int hq = blockIdx.y;       // head quarter
  const size_t row0 = (size_t)blk * 64;
  const int tid = threadIdx.x;
  float s = 0.f;
  #pragma unroll 1
  for (int batch = 0; batch < 8; ++batch) {
    __syncthreads();
    const float* src = projT + (row0 + batch * 8) * 1152;
    #pragma unroll
    for (int i = 0; i < 9; ++i) {
      int idx = i * 256 + tid;
      int r = idx / 288, col = idx - r * 288;
      int gcol = (col < 32) ? col : (32 + hq * 256 + (col - 32));
      lds[idx] = src[r * 1152 + gcol];
    }
    __syncthreads();
    int hl = tid >> 5, d = tid & 31;
    #pragma unroll
    for (int r = 0; r < 8; ++r)
      s += lds[r * 288 + hq * 8 + hl] * lds[r * 288 + 32 + hl * 32 + d];
  }
  S[(size_t)blk * 1024 + hq * 256 + tid] = s;
}

// ---------------------------------------------------------------------------
// RoPE apply, one block per (b,c,h).
__global__ __launch_bounds__(256) void rope_kernel(
    bf16* proj, const float* __restrict__ projT, const float* __restrict__ S)
{
  __shared__ float angs[64 * 33], angc[64 * 33];
  const int blk = blockIdx.x;
  const int b = blk >> 11, c = (blk >> 5) & 63, h = blk & 31;
  const size_t t0 = (size_t)b * 4096 + c * 64;
  const int w = threadIdx.x >> 6, lane = threadIdx.x & 63;
  const float* tr = projT + (t0 + lane) * 1152;
  float dtv = tr[h];
  const float* thp = tr + 32 + h * 32 + w * 8;
  float4 th0 = *(const float4*)thp;
  float4 th1 = *(const float4*)(thp + 4);
  const float* Sp = S + (size_t)(b * 64 + lane) * 1024 + h * 32 + w * 8;
  float4 S0 = *(const float4*)Sp;
  float4 S1 = *(const float4*)(Sp + 4);
  float th[8] = { th0.x, th0.y, th0.z, th0.w, th1.x, th1.y, th1.z, th1.w };
  float Sv[8] = { S0.x, S0.y, S0.z, S0.w, S1.x, S1.y, S1.z, S1.w };
  #pragma unroll 1
  for (int j = 0; j < 8; ++j) {
    int d = w * 8 + j;
    float sv = (lane < c) ? Sv[j] : 0.f;
    float off = warp_sum64(sv);
    float v = dtv * th[j];
    #pragma unroll
    for (int o = 1; o < 64; o <<= 1) { float u = __shfl_up(v, o); if (lane >= o) v += u; }
    float ang = off + v;
    float sn, cs;
    sincosf(ang, &sn, &cs);
    angs[lane * 33 + d] = sn;
    angc[lane * 33 + d] = cs;
  }
  __syncthreads();
  const int tt = threadIdx.x >> 2, q = threadIdx.x & 3;
  const size_t base = (t0 + tt) * 8192 + 4096 + h * 64 + q * 16;
  #pragma unroll
  for (int m = 0; m < 2; ++m) {   // m=0: B, m=1: C
    bf16* p = proj + base + m * 2048;
    bf16x8 v0 = *(const bf16x8*)(p);
    bf16x8 v1 = *(const bf16x8*)(p + 8);
    bf16x8 r0, r1;
    #pragma unroll
    for (int pp = 0; pp < 4; ++pp) {
      int d = q * 8 + pp;
      float e1 = (float)v0[2 * pp], e2 = (float)v0[2 * pp + 1];
      float sn = angs[tt * 33 + d], cs = angc[tt * 33 + d];
      r0[2 * pp]     = (bf16)(cs * e1 - sn * e2);
      r0[2 * pp + 1] = (bf16)(sn * e1 + cs * e2);
    }
    #pragma unroll
    for (int pp = 0; pp < 4; ++pp) {
      int d = q * 8 + 4 + pp;
      float e1 = (float)v1[2 * pp], e2 = (float)v1[2 * pp + 1];
      float sn = angs[tt * 33 + d], cs = angc[tt * 33 + d];
      r1[2 * pp]     = (bf16)(cs * e1 - sn * e2);
      r1[2 * pp + 1] = (bf16)(sn * e1 + cs * e2);
    }
    *(bf16x8*)(p) = r0;
    *(bf16x8*)(p + 8) = r1;
  }
}

// ---------------------------------------------------------------------------
// SSD stage 1 (MFMA), one block per (b,c,h) with blk = b*2048+c*32+h.
__global__ __launch_bounds__(256) void ssd1_kernel(
    const bf16* __restrict__ proj, const float* __restrict__ a_buf,
    bf16* __restrict__ Bx, bf16* __restrict__ states,
    float* __restrict__ rowsum, float* __restrict__ expac, float* __restrict__ dchunk)
{
  __shared__ bf16 Xs[64 * 72], Bs[64 * 72];
  __shared__ float acum[64], dsv[64];
  const int blk = blockIdx.x;
  const int h = blk & 31;
  const size_t bs0 = ((size_t)(blk >> 5)) * 64;
  const int tid = threadIdx.x;
  const int l = tid >> 2, p0 = (tid & 3) * 16;
  {
    const bf16* xrow = proj + (bs0 + l) * 8192 + 2048 + h * 64 + p0;
    *(bf16x8*)&Xs[l * 72 + p0]     = ((const bf16x8*)xrow)[0];
    *(bf16x8*)&Xs[l * 72 + p0 + 8] = ((const bf16x8*)xrow)[1];
    const bf16* brow = proj + (bs0 + l) * 8192 + 4096 + h * 64 + p0;
    *(bf16x8*)&Bs[l * 72 + p0]     = ((const bf16x8*)brow)[0];
    *(bf16x8*)&Bs[l * 72 + p0 + 8] = ((const bf16x8*)brow)[1];
  }
  if (tid < 64) {
    float v = a_buf[(bs0 + tid) * 32 + h];
    #pragma unroll
    for (int o = 1; o < 64; o <<= 1) { float u = __shfl_up(v, o); if (tid >= o) v += u; }
    acum[tid] = v;
    float a63 = __shfl(v, 63);
    dsv[tid] = expf(a63 - v);
    expac[(size_t)blk * 64 + tid] = expf(v);
    if (tid == 63) dchunk[blk] = expf(v);
  }
  __syncthreads();
  {
    float al = acum[l];
    float rs = 0.f;
    for (int s = tid & 3; s <= l; s += 4) rs += expf(al - acum[s]);
    rs += __shfl_xor(rs, 1);
    rs += __shfl_xor(rs, 2);
    if ((tid & 3) == 0) rowsum[(size_t)blk * 64 + l] = rs + (float)(63 - l);
  }
  const int wv = tid >> 6, lane = tid & 63;
  const int mi = lane & 15, kq = lane >> 4;
  const int m0 = wv * 16;
  fx4 accB[4], accS[4];
  #pragma unroll
  for (int j4 = 0; j4 < 4; ++j4) { fx4 z = {0.f,0.f,0.f,0.f}; accB[j4] = z; accS[j4] = z; }
  #pragma unroll
  for (int kk = 0; kk < 2; ++kk) {
    const int lb = kk * 32 + kq * 8;
    bf16x8 aX, aXd;
    #pragma unroll
    for (int j = 0; j < 8; ++j) {
      bf16 xv = Xs[(lb + j) * 72 + m0 + mi];
      aX[j] = xv;
      aXd[j] = (bf16)((float)xv * dsv[lb + j]);
    }
    #pragma unroll
    for (int j4 = 0; j4 < 4; ++j4) {
      bf16x8 bB;
      #pragma unroll
      for (int j = 0; j < 8; ++j) bB[j] = Bs[(lb + j) * 72 + j4 * 16 + mi];
      accB[j4] = __builtin_amdgcn_mfma_f32_16x16x32_bf16(aX, bB, accB[j4], 0, 0, 0);
      accS[j4] = __builtin_amdgcn_mfma_f32_16x16x32_bf16(aXd, bB, accS[j4], 0, 0, 0);
    }
  }
  const size_t obase = (size_t)blk * 4096;
  #pragma unroll
  for (int j4 = 0; j4 < 4; ++j4) {
    #pragma unroll
    for (int r = 0; r < 4; ++r) {
      int p = m0 + kq * 4 + r;
      int n = j4 * 16 + mi;
      Bx[obase + p * 64 + n] = (bf16)accB[j4][r];
      states[obase + p * 64 + n] = (bf16)accS[j4][r];
    }
  }
}

// ---------------------------------------------------------------------------
// SSD stage 2: inclusive scan over chunks (f32 carry, bf16 storage).
__global__ __launch_bounds__(128) void ssd2_kernel(
    bf16* __restrict__ states, const float* __restrict__ dchunk)
{
  const int blk = blockIdx.x;  // 1024 = b(2) x h(32) x q(16)
  const int b = blk >> 9, rest = blk & 511;
  const int h = rest >> 4, q = rest & 15;
  const int e0 = q * 256 + threadIdx.x * 2;
  float fs0 = 0.f, fs1 = 0.f;
  #pragma unroll 2
  for (int c = 0; c < 64; ++c) {
    size_t idx = ((size_t)(b * 2048 + c * 32 + h) * 4096) + e0;
    float dec = dchunk[b * 2048 + c * 32 + h];
    bf16x2 st = *(const bf16x2*)(states + idx);
    fs0 = fs0 * dec + (float)st[0];
    fs1 = fs1 * dec + (float)st[1];
    bf16x2 o = { (bf16)fs0, (bf16)fs1 };
    *(bf16x2*)(states + idx) = o;
  }
}

// ---------------------------------------------------------------------------
// SSD stage 3 (MFMA), one block per (b,c,h).
__global__ __launch_bounds__(256) void ssd3_kernel(
    bf16* proj, const bf16* __restrict__ Bx, const bf16* __restrict__ FS,
    const float* __restrict__ rowsum, const float* __restrict__ expac,
    const float* __restrict__ xsum, const float* __restrict__ D_param)
{
  __shared__ bf16 Cs[64 * 72], BxS[64 * 72], FSs[64 * 72];
  __shared__ float rs_s[64], ea_s[64], sk_s[64];
  const int blk = blockIdx.x;
  const int h = blk & 31;
  const size_t bs0 = ((size_t)(blk >> 5)) * 64;
  const int tid = threadIdx.x;
  const int l = tid >> 2, q0 = (tid & 3) * 16;
  {
    const bf16* crow = proj + (bs0 + l) * 8192 + 6144 + h * 64 + q0;
    *(bf16x8*)&Cs[l * 72 + q0]     = ((const bf16x8*)crow)[0];
    *(bf16x8*)&Cs[l * 72 + q0 + 8] = ((const bf16x8*)crow)[1];
    size_t mb = (size_t)blk * 4096 + l * 64 + q0;
    *(bf16x8*)&BxS[l * 72 + q0]     = ((const bf16x8*)(Bx + mb))[0];
    *(bf16x8*)&BxS[l * 72 + q0 + 8] = ((const bf16x8*)(Bx + mb))[1];
    *(bf16x8*)&FSs[l * 72 + q0]     = ((const bf16x8*)(FS + mb))[0];
    *(bf16x8*)&FSs[l * 72 + q0 + 8] = ((const bf16x8*)(FS + mb))[1];
  }
  if (tid < 64) {
    rs_s[tid] = rowsum[(size_t)blk * 64 + tid];
    ea_s[tid] = expac[(size_t)blk * 64 + tid];
    sk_s[tid] = D_param[h] * xsum[(bs0 + tid) * 32 + h];
  }
  __syncthreads();
  const int wv = tid >> 6, lane = tid & 63;
  const int mi = lane & 15, kq = lane >> 4;
  const int m0 = wv * 16;
  fx4 acc1[4], acc2[4];
  #pragma unroll
  for (int j4 = 0; j4 < 4; ++j4) { fx4 z = {0.f,0.f,0.f,0.f}; acc1[j4] = z; acc2[j4] = z; }
  #pragma unroll
  for (int kk = 0; kk < 2; ++kk) {
    bf16x8 aC = *(const bf16x8*)&Cs[(m0 + mi) * 72 + kk * 32 + kq * 8];
    #pragma unroll
    for (int j4 = 0; j4 < 4; ++j4) {
      bf16x8 bx = *(const bf16x8*)&BxS[(j4 * 16 + mi) * 72 + kk * 32 + kq * 8];
      bf16x8 fs = *(const bf16x8*)&FSs[(j4 * 16 + mi) * 72 + kk * 32 + kq * 8];
      acc1[j4] = __builtin_amdgcn_mfma_f32_16x16x32_bf16(aC, bx, acc1[j4], 0, 0, 0);
      acc2[j4] = __builtin_amdgcn_mfma_f32_16x16x32_bf16(aC, fs, acc2[j4], 0, 0, 0);
    }
  }
  #pragma unroll
  for (int j4 = 0; j4 < 4; ++j4) {
    #pragma unroll
    for (int r = 0; r < 4; ++r) {
      int li = m0 + kq * 4 + r;
      int p = j4 * 16 + mi;
      float y = rs_s[li] * acc1[j4][r] + ea_s[li] * acc2[j4][r] + sk_s[li];
      size_t zoff = (bs0 + li) * 8192 + h * 64 + p;
      float z = (float)proj[zoff];
      proj[zoff + 2048] = (bf16)(y * z * sigmoid_f(z));
    }
  }
}

// ---------------------------------------------------------------------------
extern "C" void kernel_launch(void* const* d_in, const int* in_sizes, int n_in,
                              void* d_out, int out_size, void* d_ws, size_t ws_size,
                              hipStream_t stream) {
  (void)in_sizes; (void)n_in; (void)out_size;
  if (ws_size < WS_NEEDED) return;  // diagnostic guard: fail absmax, not SIGABRT
  const float* x       = (const float*)d_in[0];
  const float* n1w     = (const float*)d_in[1];
  const float* n2w     = (const float*)d_in[2];
  const float* W_in    = (const float*)d_in[3];
  const float* W_out   = (const float*)d_in[4];
  const float* A_log   = (const float*)d_in[5];
  const float* D_param = (const float*)d_in[6];
  const float* dt_bias = (const float*)d_in[7];
  const float* B_bias  = (const float*)d_in[8];
  const float* C_bias  = (const float*)d_in[9];
  const float* Bn_w    = (const float*)d_in[10];
  const float* Cn_w    = (const float*)d_in[11];
  const float* Wg      = (const float*)d_in[12];
  const float* Wu      = (const float*)d_in[13];
  const float* Wd      = (const float*)d_in[14];
  float* out = (float*)d_out;
  char* ws = (char*)d_ws;

  bf16*  proj   = (bf16*)(ws + OFF_PROJ);
  float* projT  = (float*)(ws + OFF_PROJT);
  bf16*  h_hi   = (bf16*)(ws + OFF_HHI);
  bf16*  h_lo   = (bf16*)(ws + OFF_HLO);
  bf16*  Wt_in  = (bf16*)(ws + OFF_WTIN);
  bf16*  Wt_hi  = (bf16*)(ws + OFF_WTHI);
  bf16*  Wt_lo  = (bf16*)(ws + OFF_WTLO);
  bf16*  Wt_out = (bf16*)(ws + OFF_WTOUT);
  bf16*  Wt_gu  = (bf16*)(ws + OFF_WTGU);
  bf16*  Wt_d   = (bf16*)(ws + OFF_WTD);
  bf16*  Bx     = (bf16*)(ws + OFF_BX);
  bf16*  states = (bf16*)(ws + OFF_STATES);
  float* a_buf  = (float*)(ws + OFF_ABUF);
  float* xsum_  = (float*)(ws + OFF_XSUM);
  float* rowsum = (float*)(ws + OFF_ROWSUM);
  float* expac  = (float*)(ws + OFF_EXPA);
  float* dchunk = (float*)(ws + OFF_DCHUNK);
  float* gamma_ = (float*)(ws + OFF_GAMMA);
  float* Ssum   = (float*)(ws + OFF_HLO);    // 512KB chunk sums (h_lo dead by then)
  bf16*  ybf    = proj + 2048;               // cols [2048,4096) of proj, lda 8192
  bf16*  mbf    = (bf16*)(ws + OFF_MBF);
  bf16*  h2bf   = h_hi;                      // reuse after proj GEMMs
  float* x2     = out;                       // x2 lives in d_out

  // --- weight transposes needed up-front ---
  transpose_cast<<<dim3(256, 32), 256, 0, stream>>>(W_in, 9248, 0, Wt_in, 1024, 8192);
  transpose_cast_hilo<<<dim3(36, 32), 256, 0, stream>>>(W_in, 9248, 8192, Wt_hi, Wt_lo, 1024, 1056);

  // --- norm1 (hi/lo split for the precision-critical dt/theta tail GEMM) ---
  rmsnorm_kernel<<<8192, 256, 0, stream>>>(x, n1w, h_hi, h_lo);

  // --- in-projection: hi/lo tail (BN=192, 384 blk = exact round, dt fused),
  //     then proj w/ fused prep ---
  gemm_tail<<<dim3(6, 64), 256, 0, stream>>>(h_hi, h_lo, Wt_hi, Wt_lo, projT,
                                             A_log, dt_bias, a_buf, gamma_);
  gemm_proj256<<<dim3(1024), 512, 0, stream>>>(h_hi, Wt_in, proj, gamma_, xsum_,
                                               Bn_w, Cn_w, B_bias, C_bias);

  // --- hierarchical RoPE ---
  chunk_sum_kernel<<<dim3(128, 4), 256, 0, stream>>>(projT, Ssum);
  rope_kernel<<<4096, 256, 0, stream>>>(proj, projT, Ssum);

  // --- SSD (MFMA) ---
  ssd1_kernel<<<4096, 256, 0, stream>>>(proj, a_buf, Bx, states, rowsum, expac, dchunk);
  ssd2_kernel<<<1024, 128, 0, stream>>>(states, dchunk);
  ssd3_kernel<<<4096, 256, 0, stream>>>(proj, Bx, states, rowsum, expac, xsum_, D_param);

  // --- late weight transposes (overlay dead states region) ---
  transpose_cast<<<dim3(32, 64), 256, 0, stream>>>(W_out, 1024, 0, Wt_out, 2048, 1024);
  transpose_cast<<<dim3(80, 32), 256, 0, stream>>>(Wg, 2560, 0, Wt_gu, 1024, 2560);
  transpose_cast<<<dim3(80, 32), 256, 0, stream>>>(Wu, 2560, 0, Wt_gu + (size_t)2560 * 1024, 1024, 2560);
  transpose_cast<<<dim3(32, 80), 256, 0, stream>>>(Wd, 1024, 0, Wt_d, 2560, 1024);

  // --- out-projection + residual (x2 -> d_out) ---
  // M=8192, N=1024, K=2048 -> grid 64x4 = 256 blocks = exactly 1 round.
  gemm128x256<2><<<dim3(256), 512, 0, stream>>>(ybf, Wt_out, x2, x, 32, 8192, 1024, 4);

  // --- MLP ---
  rmsnorm_kernel<<<8192, 256, 0, stream>>>(x2, n2w, h2bf, nullptr);
  // fused gu GEMM + SiLU: M=8192, g/u cols 2560 -> grid 64x20 = 1280 blocks
  // (= 5 exact rounds), writes mbf directly (no gubf round-trip).
  gemm_gusilu<<<dim3(1280), 512, 0, stream>>>(h2bf, Wt_gu, mbf, 20);
  // down: M=8192, N=1024, K=2560 -> grid 64x4 = 256 blocks = exactly 1 round.
  gemm128x256<2><<<dim3(256), 512, 0, stream>>>(mbf, Wt_d, out, x2, 40, 2560, 1024, 4);
}